// Round 13
// baseline (3013.582 us; speedup 1.0000x reference)
//
#include <hip/hip_runtime.h>
#include <math.h>

typedef _Float16 h2_t __attribute__((ext_vector_type(2)));

#define U_ 256
#define NN 128
#define MM 64
#define OUT_ 8
#define CLIPV 20.0f
#define IN_DIM_ 9
#define PP 268
#define B_ 128
#define T_ 130
#define TSTART 65

// ws uint4 counts / byte offsets
#define NWXQ 10240   // 4qr * 8wv * 5p * 64ln
#define NWHQ 32768   // 4qr * 64g4 * 128slot(p*8+q), kk=q*16+p
#define NWPQ 8704    // 4qr * 17cg * 128slot(p*8+q), kk=q*16+p
#define WXQ_OFF 0
#define WHQ_OFF 163840
#define WPQ_OFF 688128
#define BLH_OFF 827392
#define BPP_OFF 831488
#define COMM_OFF 832640
#define GRP_STRIDE 6144           // hC 2048 | pC 2176 | rC 512 | flags
#define COMM_SZ (64*GRP_STRIDE)
#define PREP_N (NWXQ + NWHQ + NWPQ + 256 + 272)

__device__ __forceinline__ float sigf(float x){ return 1.0f/(1.0f+__expf(-x)); }
__device__ __forceinline__ float splus(float x){ return log1pf(__expf(x)); }
__device__ __forceinline__ float clipf(float x){ return fminf(fmaxf(x,-CLIPV),CLIPV); }

#if defined(__has_builtin)
#if __has_builtin(__builtin_amdgcn_fdot2)
#define DOT2(a,b,c) __builtin_amdgcn_fdot2((a),(b),(c),false)
#endif
#endif
#ifndef DOT2
#define DOT2(a,b,c) fmaf((float)(a).x,(float)(b).x, fmaf((float)(a).y,(float)(b).y,(c)))
#endif

#define H2C(hu) __builtin_bit_cast(h2_t,(hu))
#define DOT2X4(uu, hv) { \
    a0 = DOT2(hv, H2C((uu).x), a0); a1 = DOT2(hv, H2C((uu).y), a1); \
    a2 = DOT2(hv, H2C((uu).z), a2); a3 = DOT2(hv, H2C((uu).w), a3); }
#define DGA(uu, hv) { \
    aA0 = DOT2(hv, H2C((uu).x), aA0); aA1 = DOT2(hv, H2C((uu).y), aA1); \
    aA2 = DOT2(hv, H2C((uu).z), aA2); aA3 = DOT2(hv, H2C((uu).w), aA3); }
#define DGB(uu, hv) { \
    aB0 = DOT2(hv, H2C((uu).x), aB0); aB1 = DOT2(hv, H2C((uu).y), aB1); \
    aB2 = DOT2(hv, H2C((uu).z), aB2); aB3 = DOT2(hv, H2C((uu).w), aB3); }

__device__ __forceinline__ unsigned packh2(float a, float b){
    h2_t v; v.x = (_Float16)a; v.y = (_Float16)b;
    return __builtin_bit_cast(unsigned, v);
}

__global__ void prep_kernel(const float* __restrict__ W_x, const float* __restrict__ W_h,
                            const float* __restrict__ W_p, const float* __restrict__ b_lstm,
                            const float* __restrict__ b_p,
                            uint4* __restrict__ wxq, uint4* __restrict__ whq,
                            uint4* __restrict__ wpq,
                            float4* __restrict__ blh, float* __restrict__ bpp)
{
    for (int idx = blockIdx.x*blockDim.x + threadIdx.x; idx < PREP_N; idx += gridDim.x*blockDim.x){
        if (idx < NWXQ){
            int qr = idx/2560, rem = idx - qr*2560;
            int wv = rem/320, r2 = rem - wv*320, p = r2>>6, ln = r2&63;
            int u = qr*64 + wv*8 + (ln>>3), q = ln&7, kk = q*5+p;
            int k0 = 2*kk, k1 = k0+1;
            unsigned c[4];
            #pragma unroll
            for (int gg=0; gg<4; ++gg){
                int col = gg*256 + u;
                float f0 = (k0<64) ? W_x[(9+k0)*1024+col] : (k0<73 ? W_x[(k0-64)*1024+col] : 0.f);
                float f1 = (k1<64) ? W_x[(9+k1)*1024+col] : (k1<73 ? W_x[(k1-64)*1024+col] : 0.f);
                c[gg] = packh2(f0,f1);
            }
            wxq[idx] = make_uint4(c[0],c[1],c[2],c[3]);
        } else if (idx < NWXQ + NWHQ){
            int e = idx - NWXQ;
            int qr = e>>13, rem = e&8191, g4 = rem>>7, s = rem&127;
            int p = s>>3, q = s&7, kk = q*16+p, u = qr*64+g4;
            unsigned c[4];
            #pragma unroll
            for (int gg=0; gg<4; ++gg){
                int col = gg*256 + u;
                c[gg] = packh2(W_h[(2*kk)*1024+col], W_h[(2*kk+1)*1024+col]);
            }
            whq[e] = make_uint4(c[0],c[1],c[2],c[3]);
        } else if (idx < NWXQ + NWHQ + NWPQ){
            int e = idx - NWXQ - NWHQ;
            int qr = e/2176, rem = e - qr*2176, cg = rem>>7, s = rem&127;
            int p = s>>3, q = s&7, kk = q*16+p;
            unsigned c[4];
            #pragma unroll
            for (int jj=0; jj<4; ++jj){
                int cl = cg*4+jj;
                int pc = qr*67 + cl;
                c[jj] = (cl<67 && pc<PP) ? packh2(W_p[(2*kk)*PP+pc], W_p[(2*kk+1)*PP+pc]) : 0u;
            }
            wpq[e] = make_uint4(c[0],c[1],c[2],c[3]);
        } else if (idx < NWXQ + NWHQ + NWPQ + 256){
            int u = idx - NWXQ - NWHQ - NWPQ;
            blh[u] = make_float4(b_lstm[u], b_lstm[256+u], b_lstm[512+u], b_lstm[768+u]);
        } else {
            int j = idx - NWXQ - NWHQ - NWPQ - 256;
            bpp[j] = (j < PP) ? b_p[j] : 0.f;
        }
    }
}

__device__ __forceinline__ float decodeP(int rc, float p){
    if (rc < 64 || (rc >= 70 && rc < 134) || rc >= 204) return tanhf(p);
    if (rc >= 140 && rc < 204) return sigf(p);
    return p;
}

__global__ __launch_bounds__(1024,1) void ntm_kernel(
    const float* __restrict__ inputs,
    const float* __restrict__ W_o, const float* __restrict__ b_o,
    const float* __restrict__ r0, const float* __restrict__ w0,
    const uint4* __restrict__ wxq, const uint4* __restrict__ whq,
    const uint4* __restrict__ wpq,
    const float4* __restrict__ blh, const float* __restrict__ bpp,
    char* comm, float* __restrict__ out)
{
    const int bid = blockIdx.x;
    const int qr = bid >> 6, g = bid & 63;      // group blocks {g,g+64,g+128,g+192}: same XCD
    const int tb = qr >> 1;                     // tail batch index within group (0 or 1)
    const int bT = 2*g + tb;                    // global tail batch
    const int t = threadIdx.x, wv = t>>6, ln = t&63;

    char* cbg = comm + g*GRP_STRIDE;
    volatile float* hC  = (volatile float*)(cbg);           // [qr][beta][64]
    volatile float* pC  = (volatile float*)(cbg + 2048);    // [qr][beta][68]
    volatile float* rC  = (volatile float*)(cbg + 4224);    // [beta][64]
    volatile int* flg1  = (volatile int*)(cbg + 4736);
    volatile int* flg2  = (volatile int*)(cbg + 4800);
    volatile int* flg3  = (volatile int*)(cbg + 4864);

    __shared__ uint4 wxL[2560];          // 40KB pinned W_x quarter
    __shared__ float Mem[NN][MM+1];      // tail-batch NTM memory
    __shared__ float4 gpart4[2][64];
    __shared__ float4 blhL[64];
    __shared__ float hbuf[2][U_];
    __shared__ float cbuf[2][64];
    __shared__ h2_t  hb2[2][128] __attribute__((aligned(16)));
    __shared__ h2_t  xr2[2][40] __attribute__((aligned(16)));
    __shared__ float prmS[12];
    __shared__ float scal[12];
    __shared__ float kv[2][MM], ebuf[MM], abuf[MM];
    __shared__ float innr[2][NN], Mn[NN], wgs[2][NN], wtab[2][NN];
    __shared__ float rpart[16][MM];
    __shared__ float jpart[OUT_];

    // ---- init ----
    for (int i=t; i<2560; i+=1024) wxL[i] = wxq[qr*2560 + i];
    for (int i=t; i<NN*MM; i+=1024) Mem[i>>6][i&63] = 1e-6f;
    if (t < 128){
        gpart4[t>>6][t&63] = make_float4(0.f,0.f,0.f,0.f);
        cbuf[t>>6][t&63] = 0.f;
        Mn[t] = 8e-6f;
    }
    if (t < 64) blhL[t] = blh[qr*64+t];
    if (t >= 128 && t < 256){  // wtab = softmax(w0) (batch-independent)
        int h = (t-128)>>6, l = t&63;
        float v0 = w0[h*NN + l], v1 = w0[h*NN + l + 64];
        float mx = fmaxf(v0,v1);
        for (int off=32; off>=1; off>>=1) mx = fmaxf(mx, __shfl_xor(mx, off));
        float e0 = __expf(v0-mx), e1 = __expf(v1-mx);
        float s = e0+e1;
        for (int off=32; off>=1; off>>=1) s += __shfl_xor(s, off);
        wtab[h][l] = e0/s; wtab[h][l+64] = e1/s;
    }
    if (t >= 256 && t < 336){   // xr2 init for both batches
        int p = t-256;          // [0,80)
        int beta = p/40, pi = p - beta*40;
        int bb = 2*g + beta;
        h2_t v;
        if (pi < 32){ v.x = (_Float16)tanhf(r0[2*pi]); v.y = (_Float16)tanhf(r0[2*pi+1]); }
        else if (pi < 37){
            int e0 = 2*(pi-32), e1 = e0+1;
            float f0 = (e0<IN_DIM_) ? inputs[bb*T_*IN_DIM_ + e0] : 0.f;
            float f1 = (e1<IN_DIM_) ? inputs[bb*T_*IN_DIM_ + e1] : 0.f;
            v.x = (_Float16)f0; v.y = (_Float16)f1;
        } else { v.x=(_Float16)0.f; v.y=(_Float16)0.f; }
        xr2[beta][pi] = v;
    }
    __syncthreads();

    for (int step=0; step<T_; ++step){
        // ---- B: quarter-gates for BOTH batches from pinned wx; fused LSTM ----
        {
            const int beta = t>>9, t5 = t&511;
            const int wvb = t5>>6, lnb = t5&63;
            const int uq = wvb*8 + (lnb>>3), qb = lnb&7;
            const uint4* wb = wxL + wvb*320;
            float a0=0.f,a1=0.f,a2=0.f,a3=0.f;
            #pragma unroll
            for (int p=0; p<5; ++p){
                uint4 u = wb[p*64 + lnb];
                h2_t xv = xr2[beta][qb*5+p];
                DOT2X4(u, xv);
            }
            a0 += __shfl_xor(a0,1); a1 += __shfl_xor(a1,1);
            a2 += __shfl_xor(a2,1); a3 += __shfl_xor(a3,1);
            a0 += __shfl_xor(a0,2); a1 += __shfl_xor(a1,2);
            a2 += __shfl_xor(a2,2); a3 += __shfl_xor(a3,2);
            a0 += __shfl_xor(a0,4); a1 += __shfl_xor(a1,4);
            a2 += __shfl_xor(a2,4); a3 += __shfl_xor(a3,4);
            if (qb==0){
                float4 bb = blhL[uq];
                float4 gp = gpart4[beta][uq];
                float gi=a0+bb.x+gp.x, gf=a1+bb.y+gp.y, gg=a2+bb.z+gp.z, go=a3+bb.w+gp.w;
                float c = sigf(gf)*cbuf[beta][uq] + sigf(gi)*tanhf(gg);
                cbuf[beta][uq] = c;
                float h = sigf(go)*tanhf(c);
                hbuf[beta][qr*64+uq] = h;
                hC[(qr*2+beta)*64 + uq] = h;
            }
        }
        __syncthreads();                         // drains volatile hC stores
        if (t==0){
            flg1[qr] = step+1;
            while (flg1[(qr+1)&3] < step+1 || flg1[(qr+2)&3] < step+1 ||
                   flg1[(qr+3)&3] < step+1) __builtin_amdgcn_s_sleep(8);
        }
        __syncthreads();

        // ---- import peers' h + pack fp16 pairs ----
        if (t < 192){
            int peer = t>>6, rem = t&63, beta = rem>>5, j = rem&31;
            int qr2 = (qr+1+peer)&3;
            float v0 = hC[(qr2*2+beta)*64 + 2*j];
            float v1 = hC[(qr2*2+beta)*64 + 2*j+1];
            hbuf[beta][qr2*64+2*j] = v0; hbuf[beta][qr2*64+2*j+1] = v1;
            hb2[beta][qr2*32+j] = __builtin_bit_cast(h2_t, packh2(v0,v1));
        } else if (t < 256){
            int rem = t-192, beta = rem>>5, j = rem&31;
            float v0 = hbuf[beta][qr*64+2*j], v1 = hbuf[beta][qr*64+2*j+1];
            hb2[beta][qr*32+j] = __builtin_bit_cast(h2_t, packh2(v0,v1));
        }
        __syncthreads();

        const uint4* hA4 = (const uint4*)&hb2[0][0];
        const uint4* hB4 = (const uint4*)&hb2[1][0];

        // ---- FUSED: gpart both batches (t<512) ; wp both (512-647) ; jpart ; Mn ; x-pre ----
        if (t < 512){
            const int g4f = t>>3, qf = t&7;
            const uint4* wrow = whq + (qr*64+g4f)*128;
            uint4 ha0=hA4[qf*4+0], ha1=hA4[qf*4+1], ha2=hA4[qf*4+2], ha3=hA4[qf*4+3];
            uint4 hb0=hB4[qf*4+0], hb1=hB4[qf*4+1], hb2_=hB4[qf*4+2], hb3=hB4[qf*4+3];
            float aA0=0.f,aA1=0.f,aA2=0.f,aA3=0.f, aB0=0.f,aB1=0.f,aB2=0.f,aB3=0.f;
            {
                uint4 u0=wrow[0*8+qf], u1=wrow[1*8+qf], u2=wrow[2*8+qf], u3=wrow[3*8+qf];
                uint4 u4=wrow[4*8+qf], u5=wrow[5*8+qf], u6=wrow[6*8+qf], u7=wrow[7*8+qf];
                DGA(u0,H2C(ha0.x)); DGB(u0,H2C(hb0.x)); DGA(u1,H2C(ha0.y)); DGB(u1,H2C(hb0.y));
                DGA(u2,H2C(ha0.z)); DGB(u2,H2C(hb0.z)); DGA(u3,H2C(ha0.w)); DGB(u3,H2C(hb0.w));
                DGA(u4,H2C(ha1.x)); DGB(u4,H2C(hb1.x)); DGA(u5,H2C(ha1.y)); DGB(u5,H2C(hb1.y));
                DGA(u6,H2C(ha1.z)); DGB(u6,H2C(hb1.z)); DGA(u7,H2C(ha1.w)); DGB(u7,H2C(hb1.w));
            }
            {
                uint4 u0=wrow[8*8+qf],  u1=wrow[9*8+qf],  u2=wrow[10*8+qf], u3=wrow[11*8+qf];
                uint4 u4=wrow[12*8+qf], u5=wrow[13*8+qf], u6=wrow[14*8+qf], u7=wrow[15*8+qf];
                DGA(u0,H2C(ha2.x)); DGB(u0,H2C(hb2_.x)); DGA(u1,H2C(ha2.y)); DGB(u1,H2C(hb2_.y));
                DGA(u2,H2C(ha2.z)); DGB(u2,H2C(hb2_.z)); DGA(u3,H2C(ha2.w)); DGB(u3,H2C(hb2_.w));
                DGA(u4,H2C(ha3.x)); DGB(u4,H2C(hb3.x)); DGA(u5,H2C(ha3.y)); DGB(u5,H2C(hb3.y));
                DGA(u6,H2C(ha3.z)); DGB(u6,H2C(hb3.z)); DGA(u7,H2C(ha3.w)); DGB(u7,H2C(hb3.w));
            }
            #pragma unroll
            for (int m=1; m<8; m<<=1){
                aA0 += __shfl_xor(aA0,m); aA1 += __shfl_xor(aA1,m);
                aA2 += __shfl_xor(aA2,m); aA3 += __shfl_xor(aA3,m);
                aB0 += __shfl_xor(aB0,m); aB1 += __shfl_xor(aB1,m);
                aB2 += __shfl_xor(aB2,m); aB3 += __shfl_xor(aB3,m);
            }
            if (qf==0){
                gpart4[0][g4f] = make_float4(aA0,aA1,aA2,aA3);
                gpart4[1][g4f] = make_float4(aB0,aB1,aB2,aB3);
            }
        } else if (t < 648){
            const int tw = t-512, cg = tw>>3, qf = tw&7;
            const uint4* wrow = wpq + (qr*17+cg)*128;
            uint4 ha0=hA4[qf*4+0], ha1=hA4[qf*4+1], ha2=hA4[qf*4+2], ha3=hA4[qf*4+3];
            uint4 hb0=hB4[qf*4+0], hb1=hB4[qf*4+1], hb2_=hB4[qf*4+2], hb3=hB4[qf*4+3];
            float aA0=0.f,aA1=0.f,aA2=0.f,aA3=0.f, aB0=0.f,aB1=0.f,aB2=0.f,aB3=0.f;
            {
                uint4 u0=wrow[0*8+qf], u1=wrow[1*8+qf], u2=wrow[2*8+qf], u3=wrow[3*8+qf];
                uint4 u4=wrow[4*8+qf], u5=wrow[5*8+qf], u6=wrow[6*8+qf], u7=wrow[7*8+qf];
                DGA(u0,H2C(ha0.x)); DGB(u0,H2C(hb0.x)); DGA(u1,H2C(ha0.y)); DGB(u1,H2C(hb0.y));
                DGA(u2,H2C(ha0.z)); DGB(u2,H2C(hb0.z)); DGA(u3,H2C(ha0.w)); DGB(u3,H2C(hb0.w));
                DGA(u4,H2C(ha1.x)); DGB(u4,H2C(hb1.x)); DGA(u5,H2C(ha1.y)); DGB(u5,H2C(hb1.y));
                DGA(u6,H2C(ha1.z)); DGB(u6,H2C(hb1.z)); DGA(u7,H2C(ha1.w)); DGB(u7,H2C(hb1.w));
            }
            {
                uint4 u0=wrow[8*8+qf],  u1=wrow[9*8+qf],  u2=wrow[10*8+qf], u3=wrow[11*8+qf];
                uint4 u4=wrow[12*8+qf], u5=wrow[13*8+qf], u6=wrow[14*8+qf], u7=wrow[15*8+qf];
                DGA(u0,H2C(ha2.x)); DGB(u0,H2C(hb2_.x)); DGA(u1,H2C(ha2.y)); DGB(u1,H2C(hb2_.y));
                DGA(u2,H2C(ha2.z)); DGB(u2,H2C(hb2_.z)); DGA(u3,H2C(ha2.w)); DGB(u3,H2C(hb2_.w));
                DGA(u4,H2C(ha3.x)); DGB(u4,H2C(hb3.x)); DGA(u5,H2C(ha3.y)); DGB(u5,H2C(hb3.y));
                DGA(u6,H2C(ha3.z)); DGB(u6,H2C(hb3.z)); DGA(u7,H2C(ha3.w)); DGB(u7,H2C(hb3.w));
            }
            #pragma unroll
            for (int m=1; m<8; m<<=1){
                aA0 += __shfl_xor(aA0,m); aA1 += __shfl_xor(aA1,m);
                aA2 += __shfl_xor(aA2,m); aA3 += __shfl_xor(aA3,m);
                aB0 += __shfl_xor(aB0,m); aB1 += __shfl_xor(aB1,m);
                aB2 += __shfl_xor(aB2,m); aB3 += __shfl_xor(aB3,m);
            }
            if (qf==0){
                float avA[4] = {aA0,aA1,aA2,aA3};
                float avB[4] = {aB0,aB1,aB2,aB3};
                #pragma unroll
                for (int jj=0; jj<4; ++jj){
                    int cl = cg*4+jj;
                    if (cl < 67){
                        int pc = qr*67 + cl;
                        float bpv = bpp[pc];
                        float dvA = decodeP(pc, clipf(avA[jj] + bpv));
                        float dvB = decodeP(pc, clipf(avB[jj] + bpv));
                        pC[(qr*2+0)*68 + cl] = dvA;
                        pC[(qr*2+1)*68 + cl] = dvB;
                        float dv = tb ? dvB : dvA;
                        if (pc < 64) kv[0][pc] = dv;
                        else if (pc < 70) prmS[pc-64] = dv;
                        else if (pc < 134) kv[1][pc-70] = dv;
                        else if (pc < 140) prmS[6+pc-134] = dv;
                        else if (pc < 204) ebuf[pc-140] = dv;
                        else abuf[pc-204] = dv;
                    }
                }
            }
        } else if (t >= 656 && t < 784){
            const int o = (t-656)>>4, l16 = (t-656)&15;
            float s = 0.f;
            #pragma unroll
            for (int j=0; j<16; ++j){
                const int i = l16 + (j<<4);
                s = fmaf(hbuf[tb][i], W_o[i*OUT_ + o], s);
            }
            s += __shfl_xor(s,1); s += __shfl_xor(s,2);
            s += __shfl_xor(s,4); s += __shfl_xor(s,8);
            if (l16==0) jpart[o] = s;
        } else if (t >= 784 && t < 912){
            const int n = t-784;
            float s = 0.f;
            #pragma unroll 8
            for (int m=0; m<MM; ++m){ float v=Mem[n][m]; s=fmaf(v,v,s); }
            Mn[n] = sqrtf(s);
        } else if (t >= 912 && t < 922){
            if (step+1 < T_){
                const int p = t-912;
                const int beta = p/5, pi = p - beta*5;
                const int bb = 2*g + beta;
                const int e0 = 2*pi, e1 = e0+1;
                const float* xin = inputs + (bb*T_ + step+1)*IN_DIM_;
                h2_t v;
                v.x = (_Float16)((e0<IN_DIM_) ? xin[e0] : 0.f);
                v.y = (_Float16)((e1<IN_DIM_) ? xin[e1] : 0.f);
                xr2[beta][32+pi] = v;
            }
        }
        __syncthreads();                         // drains volatile pC stores
        if (t==0){
            flg2[qr] = step+1;
            while (flg2[(qr+1)&3] < step+1 || flg2[(qr+2)&3] < step+1 ||
                   flg2[(qr+3)&3] < step+1) __builtin_amdgcn_s_sleep(8);
        }
        __syncthreads();

        // ---- route peers' params (tail batch only) ----
        if (t < 204){
            int peer = t/68, cl = t - peer*68;
            int qr2 = (qr+1+peer)&3;
            if (cl < 67){
                int pc = qr2*67 + cl;
                float dv = pC[(qr2*2+tb)*68 + cl];
                if (pc < 64) kv[0][pc] = dv;
                else if (pc < 70) prmS[pc-64] = dv;
                else if (pc < 134) kv[1][pc-70] = dv;
                else if (pc < 140) prmS[6+pc-134] = dv;
                else if (pc < 204) ebuf[pc-140] = dv;
                else abuf[pc-204] = dv;
            }
        }
        __syncthreads();

        // ---- F: inner products + scal decode ----
        {
            const int h = t>>9, n = (t>>2)&127, qm = t&3, m0 = qm*16;
            float s = 0.f;
            #pragma unroll 8
            for (int m=m0; m<m0+16; ++m) s = fmaf(kv[h][m], Mem[n][m], s);
            s += __shfl_xor(s,1); s += __shfl_xor(s,2);
            if (qm==0) innr[h][n] = s;
        }
        if (t < 2){
            const int h = t;
            const float* ps = prmS + 6*h;
            scal[h]   = splus(ps[0]);
            scal[2+h] = sigf(ps[1]);
            float p0=ps[2], p1=ps[3], p2=ps[4];
            float mx = fmaxf(p0, fmaxf(p1, p2));
            float e0=__expf(p0-mx), e1=__expf(p1-mx), e2=__expf(p2-mx);
            float s = e0+e1+e2;
            scal[6+3*h]=e0/s; scal[7+3*h]=e1/s; scal[8+3*h]=e2/s;
            scal[4+h] = 1.f + splus(ps[5]);
        }
        __syncthreads();

        // ---- G: key norm + content softmax + interp + shift + sharpen ----
        if (t < 128){
            const int h = t>>6, l = ln;
            float kvl = kv[h][l];
            float kn2 = kvl*kvl;
            for (int off=32; off>=1; off>>=1) kn2 += __shfl_xor(kn2, off);
            float kn = sqrtf(kn2);
            float beta = scal[h], gg = scal[2+h];
            float bk0 = beta * innr[h][l]   /(kn*Mn[l]   +1e-8f);
            float bk1 = beta * innr[h][l+64]/(kn*Mn[l+64]+1e-8f);
            float mx = fmaxf(bk0,bk1);
            for (int off=32; off>=1; off>>=1) mx = fmaxf(mx, __shfl_xor(mx, off));
            float e0=__expf(bk0-mx), e1=__expf(bk1-mx);
            float s=e0+e1;
            for (int off=32; off>=1; off>>=1) s += __shfl_xor(s, off);
            float wc0=e0/s, wc1=e1/s;
            wgs[h][l]    = gg*wc0 + (1.f-gg)*wtab[h][l];
            wgs[h][l+64] = gg*wc1 + (1.f-gg)*wtab[h][l+64];
            float gamma = scal[4+h];
            float s0=scal[6+3*h], s1=scal[7+3*h], s2=scal[8+3*h];
            const int n0=l, n1=l+64;
            float wt0 = s0*wgs[h][(n0+1)&127] + s1*wgs[h][n0] + s2*wgs[h][(n0+127)&127];
            float wt1 = s0*wgs[h][(n1+1)&127] + s1*wgs[h][n1] + s2*wgs[h][(n1+127)&127];
            float wp0 = __powf(wt0, gamma), wp1 = __powf(wt1, gamma);
            float ss = wp0+wp1;
            for (int off=32; off>=1; off>>=1) ss += __shfl_xor(ss, off);
            float inv = 1.0f/(ss+1e-8f);
            wtab[h][n0] = wp0*inv; wtab[h][n1] = wp1*inv;
        }
        __syncthreads();

        // ---- H: memory write + fused read-head partials ----
        {
            const float el = ebuf[ln], al = abuf[ln];
            const int n0 = wv*8;
            float racc = 0.f;
            #pragma unroll
            for (int k=0; k<8; ++k){
                const int n = n0+k;
                float ww = wtab[1][n];
                float wr = wtab[0][n];
                float v = Mem[n][ln]*(1.0f - ww*el) + ww*al;
                Mem[n][ln] = v;
                racc = fmaf(wr, v, racc);
            }
            rpart[wv][ln] = racc;
        }
        __syncthreads();

        // ---- J: r finalize + output + r export ----
        if (t < 512){
            const int o = wv;
            float rm = 0.f;
            #pragma unroll
            for (int k=0; k<16; ++k) rm += rpart[k][ln];
            if (o==0 && (qr&1)==0) rC[tb*64+ln] = rm;
            float s = rm * W_o[(U_+ln)*OUT_ + o];
            for (int off=32; off>=1; off>>=1) s += __shfl_xor(s, off);
            if (ln==0 && (qr&1)==0 && step>=TSTART){
                float logit = clipf(s + jpart[o] + b_o[o]);
                out[((bT*(T_-TSTART)) + (step-TSTART))*OUT_ + o] = sigf(logit);
            }
        }
        __syncthreads();                         // drains volatile rC stores
        if (t==0){
            if (qr==0) flg3[0] = step+1;
            if (qr==2) flg3[1] = step+1;
            while (flg3[0] < step+1 || flg3[1] < step+1) __builtin_amdgcn_s_sleep(8);
        }
        __syncthreads();
        if (t < 128){
            const int beta = t>>6, l = t&63;
            float rv = rC[beta*64+l];
            float rv2 = __shfl_down(rv, 1);
            if (!(l&1)) xr2[beta][l>>1] = __builtin_bit_cast(h2_t, packh2(rv, rv2));
        }
        __syncthreads();
    }
}

extern "C" void kernel_launch(void* const* d_in, const int* in_sizes, int n_in,
                              void* d_out, int out_size, void* d_ws, size_t ws_size,
                              hipStream_t stream) {
    const float* inputs = (const float*)d_in[0];
    const float* W_x    = (const float*)d_in[1];
    const float* W_h    = (const float*)d_in[2];
    const float* b_lstm = (const float*)d_in[3];
    const float* W_p    = (const float*)d_in[4];
    const float* b_p    = (const float*)d_in[5];
    const float* W_o    = (const float*)d_in[6];
    const float* b_o    = (const float*)d_in[7];
    const float* r0     = (const float*)d_in[8];
    const float* w0     = (const float*)d_in[9];
    float* out = (float*)d_out;

    char* ws = (char*)d_ws;
    uint4*  wxq = (uint4*)(ws + WXQ_OFF);
    uint4*  whq = (uint4*)(ws + WHQ_OFF);
    uint4*  wpq = (uint4*)(ws + WPQ_OFF);
    float4* blh = (float4*)(ws + BLH_OFF);
    float*  bpp = (float*)(ws + BPP_OFF);
    char*   comm = ws + COMM_OFF;

    hipMemsetAsync(comm, 0, COMM_SZ, stream);
    prep_kernel<<<512, 256, 0, stream>>>(W_x, W_h, W_p, b_lstm, b_p, wxq, whq, wpq, blh, bpp);
    ntm_kernel<<<256, 1024, 0, stream>>>(inputs, W_o, b_o, r0, w0,
                                         wxq, whq, wpq, blh, bpp, comm, out);
}

// Round 14
// 2276.414 us; speedup vs baseline: 1.3238x; 1.3238x over previous
//
#include <hip/hip_runtime.h>
#include <math.h>

typedef _Float16 h2_t __attribute__((ext_vector_type(2)));

#define U_ 256
#define NN 128
#define MM 64
#define OUT_ 8
#define CLIPV 20.0f
#define IN_DIM_ 9
#define PP 268
#define B_ 128
#define T_ 130
#define TSTART 65

// ws element counts / byte offsets
#define NWX2 10240      // 2hf * 16wv * 5p * 64ln        (uint4, conflict-free pinned)
#define NWHG 32768      // 2hf * 128g4 * 128slot(p*8+q)  (uint4, kk=q*16+p)
#define NWPG 8704       // 2hf * 34cg * 128slot(p*8+q)   (uint4, kk=q*16+p)
#define WX2_OFF 0
#define WHG_OFF 163840
#define WPG_OFF 688128
#define BLH_OFF 827392
#define BPP_OFF 831488
#define COMM_OFF 832640
#define COMM_STRIDE 2176          // hA512|hB512|pA544|pB544|flags|pad
#define COMM_SZ (B_*COMM_STRIDE)
#define PREP_N (NWX2 + NWHG + NWPG + 256 + 272)

__device__ __forceinline__ float sigf(float x){ return 1.0f/(1.0f+__expf(-x)); }
__device__ __forceinline__ float splus(float x){ return log1pf(__expf(x)); }
__device__ __forceinline__ float clipf(float x){ return fminf(fmaxf(x,-CLIPV),CLIPV); }

#if defined(__has_builtin)
#if __has_builtin(__builtin_amdgcn_fdot2)
#define DOT2(a,b,c) __builtin_amdgcn_fdot2((a),(b),(c),false)
#endif
#endif
#ifndef DOT2
#define DOT2(a,b,c) fmaf((float)(a).x,(float)(b).x, fmaf((float)(a).y,(float)(b).y,(c)))
#endif

#define DOT2X4(uu, hv) { \
    a0 = DOT2(hv, __builtin_bit_cast(h2_t,(uu).x), a0); \
    a1 = DOT2(hv, __builtin_bit_cast(h2_t,(uu).y), a1); \
    a2 = DOT2(hv, __builtin_bit_cast(h2_t,(uu).z), a2); \
    a3 = DOT2(hv, __builtin_bit_cast(h2_t,(uu).w), a3); }
#define DOT2P(uu, hv) { \
    pa0 = DOT2(hv, __builtin_bit_cast(h2_t,(uu).x), pa0); \
    pa1 = DOT2(hv, __builtin_bit_cast(h2_t,(uu).y), pa1); \
    pa2 = DOT2(hv, __builtin_bit_cast(h2_t,(uu).z), pa2); \
    pa3 = DOT2(hv, __builtin_bit_cast(h2_t,(uu).w), pa3); }
#define H2C(hu) __builtin_bit_cast(h2_t,(hu))

__device__ __forceinline__ unsigned packh2(float a, float b){
    h2_t v; v.x = (_Float16)a; v.y = (_Float16)b;
    return __builtin_bit_cast(unsigned, v);
}

__global__ void prep_kernel(const float* __restrict__ W_x, const float* __restrict__ W_h,
                            const float* __restrict__ W_p, const float* __restrict__ b_lstm,
                            const float* __restrict__ b_p,
                            uint4* __restrict__ wx2, uint4* __restrict__ wh2,
                            uint4* __restrict__ wp2,
                            float4* __restrict__ blh, float* __restrict__ bpp)
{
    for (int idx = blockIdx.x*blockDim.x + threadIdx.x; idx < PREP_N; idx += gridDim.x*blockDim.x){
        if (idx < NWX2){
            // conflict-free pinned layout: [hf][wv][p][ln]
            int hf = idx/5120, rem = idx - hf*5120;
            int wv = rem/320, r2 = rem - wv*320, p = r2>>6, ln = r2&63;
            int g4 = wv*8 + (ln>>3), q = ln&7, kk = q*5+p;
            int k0 = 2*kk, k1 = k0+1;
            unsigned c[4];
            #pragma unroll
            for (int g=0; g<4; ++g){
                int col = g*256 + hf*128 + g4;
                float f0 = (k0<64) ? W_x[(9+k0)*1024+col] : (k0<73 ? W_x[(k0-64)*1024+col] : 0.f);
                float f1 = (k1<64) ? W_x[(9+k1)*1024+col] : (k1<73 ? W_x[(k1-64)*1024+col] : 0.f);
                c[g] = packh2(f0,f1);
            }
            wx2[idx] = make_uint4(c[0],c[1],c[2],c[3]);
        } else if (idx < NWX2 + NWHG){
            int e = idx - NWX2;
            int hf = e>>14, rem = e&16383, g4 = rem>>7, s = rem&127;
            int p = s>>3, q = s&7, kk = q*16+p;
            unsigned c[4];
            #pragma unroll
            for (int g=0; g<4; ++g){
                int col = g*256 + hf*128 + g4;
                c[g] = packh2(W_h[(2*kk)*1024+col], W_h[(2*kk+1)*1024+col]);
            }
            wh2[e] = make_uint4(c[0],c[1],c[2],c[3]);
        } else if (idx < NWX2 + NWHG + NWPG){
            int e = idx - NWX2 - NWHG;
            int hf = e/4352, rem = e - hf*4352, cg = rem>>7, s = rem&127;
            int p = s>>3, q = s&7, kk = q*16+p;
            unsigned c[4];
            #pragma unroll
            for (int g=0; g<4; ++g){
                int cl = cg*4+g, rc = hf*134+cl;
                c[g] = (cl<134) ? packh2(W_p[(2*kk)*PP+rc], W_p[(2*kk+1)*PP+rc]) : 0u;
            }
            wp2[e] = make_uint4(c[0],c[1],c[2],c[3]);
        } else if (idx < NWX2 + NWHG + NWPG + 256){
            int u = idx - NWX2 - NWHG - NWPG;
            blh[u] = make_float4(b_lstm[u], b_lstm[256+u], b_lstm[512+u], b_lstm[768+u]);
        } else {
            int j = idx - NWX2 - NWHG - NWPG - 256;
            bpp[j] = (j < PP) ? b_p[j] : 0.f;
        }
    }
}

__device__ __forceinline__ float decodeP(int rc, float p){
    if (rc < 64 || (rc >= 70 && rc < 134) || rc >= 204) return tanhf(p);
    if (rc >= 140 && rc < 204) return sigf(p);
    return p;
}

__global__ __launch_bounds__(1024,4) void ntm_kernel(
    const float* __restrict__ inputs,
    const float* __restrict__ W_o, const float* __restrict__ b_o,
    const float* __restrict__ r0, const float* __restrict__ w0,
    const uint4* __restrict__ wx2, const uint4* __restrict__ whg,
    const uint4* __restrict__ wpg,
    const float4* __restrict__ blh, const float* __restrict__ bpp,
    char* comm, float* __restrict__ out)
{
    const int bid = blockIdx.x, hf = bid>>7, b = bid&127;
    const int t = threadIdx.x, wv = t>>6, ln = t&63;
    const int g4 = t>>3, q = t&7;

    char* cb = comm + b*COMM_STRIDE;
    volatile float* hOwn = (volatile float*)(cb + hf*512);
    volatile float* hOth = (volatile float*)(cb + (hf^1)*512);
    volatile float* pOwn = (volatile float*)(cb + 1024 + hf*544);
    volatile float* pOth = (volatile float*)(cb + 1024 + (hf^1)*544);
    volatile int*   flg  = (volatile int*)(cb + 2112);   // [f1A,f1B,f2A,f2B]

    __shared__ uint4 wxL[5120];          // 80KB pinned W_x half (conflict-free)
    __shared__ float Mem[NN][MM+1];
    __shared__ float4 gpart4[128];
    __shared__ float4 blhL[128];
    __shared__ float hbuf[U_];
    __shared__ float cbuf[128];
    __shared__ h2_t  hb2[128] __attribute__((aligned(16)));
    __shared__ h2_t  xr2[40] __attribute__((aligned(16)));
    __shared__ float prmS[12];
    __shared__ float scal[12];
    __shared__ float kv[2][MM], ebuf[MM], abuf[MM];
    __shared__ float innr[2][NN], Mn[NN], wgs[2][NN], wtab[2][NN];
    __shared__ float rpart[16][MM];
    __shared__ float jpart[OUT_];

    // ---- init ----
    for (int i=t; i<5120; i+=1024) wxL[i] = wx2[hf*5120 + i];
    for (int i=t; i<NN*MM; i+=1024) Mem[i>>6][i&63] = 1e-6f;
    if (t < 128){
        gpart4[t] = make_float4(0.f,0.f,0.f,0.f);
        blhL[t] = blh[hf*128+t];
        cbuf[t] = 0.f;
        Mn[t] = 8e-6f;
        h2_t z; z.x=(_Float16)0.f; z.y=(_Float16)0.f; hb2[t] = z;
    }
    if (t < U_) hbuf[t] = 0.f;
    if (t >= 128 && t < 256){  // wtab = softmax(w0)
        int h = (t-128)>>6, l = t&63;
        float v0 = w0[h*NN + l], v1 = w0[h*NN + l + 64];
        float mx = fmaxf(v0,v1);
        for (int off=32; off>=1; off>>=1) mx = fmaxf(mx, __shfl_xor(mx, off));
        float e0 = __expf(v0-mx), e1 = __expf(v1-mx);
        float s = e0+e1;
        for (int off=32; off>=1; off>>=1) s += __shfl_xor(s, off);
        wtab[h][l] = e0/s; wtab[h][l+64] = e1/s;
    }
    if (t >= 256 && t < 296){
        int p = t-256;
        h2_t v;
        if (p < 32){ v.x = (_Float16)tanhf(r0[2*p]); v.y = (_Float16)tanhf(r0[2*p+1]); }
        else if (p < 37){
            int e0 = 2*(p-32), e1 = e0+1;
            float f0 = (e0<IN_DIM_) ? inputs[b*T_*IN_DIM_ + e0] : 0.f;
            float f1 = (e1<IN_DIM_) ? inputs[b*T_*IN_DIM_ + e1] : 0.f;
            v.x = (_Float16)f0; v.y = (_Float16)f1;
        } else { v.x=(_Float16)0.f; v.y=(_Float16)0.f; }
        xr2[p] = v;
    }
    __syncthreads();

    const uint4* wrowG = whg + hf*16384 + g4*128;

    for (int step=0; step<T_; ++step){
        // ---- pre-issue gpart weight batch-0: drains under B + sync1 ----
        uint4 pw0=wrowG[0*8+q], pw1=wrowG[1*8+q], pw2=wrowG[2*8+q], pw3=wrowG[3*8+q];
        uint4 pw4=wrowG[4*8+q], pw5=wrowG[5*8+q], pw6=wrowG[6*8+q], pw7=wrowG[7*8+q];

        // ---- B: gates from pinned wx (conflict-free) + gpart + bias, fused LSTM ----
        {
            const uint4* wb = wxL + wv*320;
            float a0=0.f,a1=0.f,a2=0.f,a3=0.f;
            #pragma unroll
            for (int p=0; p<5; ++p){
                uint4 u = wb[p*64 + ln];
                h2_t xv = xr2[q*5+p];
                DOT2X4(u, xv);
            }
            #pragma unroll
            for (int m=1; m<8; m<<=1){
                a0 += __shfl_xor(a0,m); a1 += __shfl_xor(a1,m);
                a2 += __shfl_xor(a2,m); a3 += __shfl_xor(a3,m);
            }
            if (q==0){
                float4 bb = blhL[g4]; float4 gp = gpart4[g4];
                float gi=a0+bb.x+gp.x, gf=a1+bb.y+gp.y, gg=a2+bb.z+gp.z, go=a3+bb.w+gp.w;
                float c = sigf(gf)*cbuf[g4] + sigf(gi)*tanhf(gg);
                cbuf[g4] = c;
                float h = sigf(go)*tanhf(c);
                hbuf[hf*128+g4] = h;
                hOwn[g4] = h;
            }
        }
        __syncthreads();                          // drains volatile h stores + pw batch
        if (t==0){
            flg[hf] = step+1;
            while (flg[hf^1] < step+1) __builtin_amdgcn_s_sleep(1);
        }
        __syncthreads();
        // pull partner h; build fp16 h pairs
        if (t < 128){
            float hv = hOth[t];
            hbuf[(hf^1)*128 + t] = hv;
            float hv2 = __shfl_down(hv, 1);
            if (!(t&1)){ h2_t vv; vv.x=(_Float16)hv; vv.y=(_Float16)hv2; hb2[(hf^1)*64 + (t>>1)] = vv; }
        } else if (t < 192){
            int jj = t-128;
            h2_t vv; vv.x=(_Float16)hbuf[hf*128+2*jj]; vv.y=(_Float16)hbuf[hf*128+2*jj+1];
            hb2[hf*64+jj] = vv;
        }
        __syncthreads();

        const uint4* hb2q = (const uint4*)hb2;

        // ---- FUSED: gpart (all threads; batch-0 pre-issued) ; wp ; Mn ; jpart ; x-pre ----
        {
            uint4 hA = hb2q[q*4+0], hB = hb2q[q*4+1], hC = hb2q[q*4+2], hD = hb2q[q*4+3];
            float a0=0.f,a1=0.f,a2=0.f,a3=0.f;
            DOT2X4(pw0, H2C(hA.x)); DOT2X4(pw1, H2C(hA.y));
            DOT2X4(pw2, H2C(hA.z)); DOT2X4(pw3, H2C(hA.w));
            DOT2X4(pw4, H2C(hB.x)); DOT2X4(pw5, H2C(hB.y));
            DOT2X4(pw6, H2C(hB.z)); DOT2X4(pw7, H2C(hB.w));
            {
                uint4 u0=wrowG[8*8+q],  u1=wrowG[9*8+q],  u2=wrowG[10*8+q], u3=wrowG[11*8+q];
                uint4 u4=wrowG[12*8+q], u5=wrowG[13*8+q], u6=wrowG[14*8+q], u7=wrowG[15*8+q];
                DOT2X4(u0, H2C(hC.x)); DOT2X4(u1, H2C(hC.y));
                DOT2X4(u2, H2C(hC.z)); DOT2X4(u3, H2C(hC.w));
                DOT2X4(u4, H2C(hD.x)); DOT2X4(u5, H2C(hD.y));
                DOT2X4(u6, H2C(hD.z)); DOT2X4(u7, H2C(hD.w));
            }
            #pragma unroll
            for (int m=1; m<8; m<<=1){
                a0 += __shfl_xor(a0,m); a1 += __shfl_xor(a1,m);
                a2 += __shfl_xor(a2,m); a3 += __shfl_xor(a3,m);
            }
            if (q==0) gpart4[g4] = make_float4(a0,a1,a2,a3);
        }
        if (t < 272){
            const int cg = t>>3, qq = t&7;
            const uint4* wrow = wpg + (hf*34+cg)*128;
            uint4 hA = hb2q[qq*4+0], hB = hb2q[qq*4+1], hC = hb2q[qq*4+2], hD = hb2q[qq*4+3];
            float pa0=0.f, pa1=0.f, pa2=0.f, pa3=0.f;
            {
                uint4 u0=wrow[0*8+qq], u1=wrow[1*8+qq], u2=wrow[2*8+qq], u3=wrow[3*8+qq];
                uint4 u4=wrow[4*8+qq], u5=wrow[5*8+qq], u6=wrow[6*8+qq], u7=wrow[7*8+qq];
                DOT2P(u0, H2C(hA.x)); DOT2P(u1, H2C(hA.y));
                DOT2P(u2, H2C(hA.z)); DOT2P(u3, H2C(hA.w));
                DOT2P(u4, H2C(hB.x)); DOT2P(u5, H2C(hB.y));
                DOT2P(u6, H2C(hB.z)); DOT2P(u7, H2C(hB.w));
            }
            {
                uint4 u0=wrow[8*8+qq],  u1=wrow[9*8+qq],  u2=wrow[10*8+qq], u3=wrow[11*8+qq];
                uint4 u4=wrow[12*8+qq], u5=wrow[13*8+qq], u6=wrow[14*8+qq], u7=wrow[15*8+qq];
                DOT2P(u0, H2C(hC.x)); DOT2P(u1, H2C(hC.y));
                DOT2P(u2, H2C(hC.z)); DOT2P(u3, H2C(hC.w));
                DOT2P(u4, H2C(hD.x)); DOT2P(u5, H2C(hD.y));
                DOT2P(u6, H2C(hD.z)); DOT2P(u7, H2C(hD.w));
            }
            #pragma unroll
            for (int m=1; m<8; m<<=1){
                pa0 += __shfl_xor(pa0,m); pa1 += __shfl_xor(pa1,m);
                pa2 += __shfl_xor(pa2,m); pa3 += __shfl_xor(pa3,m);
            }
            if (qq==0){
                #pragma unroll
                for (int j=0; j<4; ++j){
                    float aj = (j==0)?pa0:((j==1)?pa1:((j==2)?pa2:pa3));
                    int cl = cg*4+j;
                    if (cl < 134){
                        int rc = hf*134+cl;
                        float pv = clipf(aj + bpp[rc]);
                        float dv = decodeP(rc, pv);
                        pOwn[cl] = dv;
                        if (rc < 64) kv[0][rc] = dv;
                        else if (rc < 70) prmS[rc-64] = dv;
                        else if (rc < 134) kv[1][rc-70] = dv;
                        else if (rc < 140) prmS[6+rc-134] = dv;
                        else if (rc < 204) ebuf[rc-140] = dv;
                        else abuf[rc-204] = dv;
                    }
                }
            }
        } else if (t < 528){
            const int idx = t-272, n = idx>>1, m0 = (idx&1)*32;
            float s = 0.f;
            #pragma unroll 8
            for (int m=m0; m<m0+32; ++m){ float v=Mem[n][m]; s=fmaf(v,v,s); }
            s += __shfl_xor(s,1);
            if (!(idx&1)) Mn[n] = sqrtf(s);
        } else if (t < 656){
            const int o = (t-528)>>4, l16 = (t-528)&15;
            float s = 0.f;
            #pragma unroll
            for (int j=0; j<16; ++j){
                const int i = l16 + (j<<4);
                s = fmaf(hbuf[i], W_o[i*OUT_ + o], s);
            }
            s += __shfl_xor(s,1); s += __shfl_xor(s,2);
            s += __shfl_xor(s,4); s += __shfl_xor(s,8);
            if (l16==0) jpart[o] = s;
        } else if (t >= 656 && t < 661){
            if (step+1 < T_){
                const int p = t-656;
                const int e0 = 2*p, e1 = e0+1;
                const float* xin = inputs + (b*T_ + step+1)*IN_DIM_;
                h2_t v;
                v.x = (_Float16)((e0<IN_DIM_) ? xin[e0] : 0.f);
                v.y = (_Float16)((e1<IN_DIM_) ? xin[e1] : 0.f);
                xr2[32+p] = v;
            }
        }
        __syncthreads();                          // drains volatile p stores
        if (t==0){
            flg[2+hf] = step+1;
            while (flg[2+(hf^1)] < step+1) __builtin_amdgcn_s_sleep(1);
        }
        __syncthreads();
        if (t < 134){                              // route partner's decoded params
            float dv = pOth[t];
            int rc = (hf^1)*134 + t;
            if (rc < 64) kv[0][rc] = dv;
            else if (rc < 70) prmS[rc-64] = dv;
            else if (rc < 134) kv[1][rc-70] = dv;
            else if (rc < 140) prmS[6+rc-134] = dv;
            else if (rc < 204) ebuf[rc-140] = dv;
            else abuf[rc-204] = dv;
        }
        __syncthreads();

        // ---- F: inner products + scal decode ----
        {
            const int h = t>>9, n = (t>>2)&127, qm = t&3, m0 = qm*16;
            float s = 0.f;
            #pragma unroll 8
            for (int m=m0; m<m0+16; ++m) s = fmaf(kv[h][m], Mem[n][m], s);
            s += __shfl_xor(s,1); s += __shfl_xor(s,2);
            if (qm==0) innr[h][n] = s;
        }
        if (t < 2){
            const int h = t;
            const float* ps = prmS + 6*h;
            scal[h]   = splus(ps[0]);
            scal[2+h] = sigf(ps[1]);
            float p0=ps[2], p1=ps[3], p2=ps[4];
            float mx = fmaxf(p0, fmaxf(p1, p2));
            float e0=__expf(p0-mx), e1=__expf(p1-mx), e2=__expf(p2-mx);
            float s = e0+e1+e2;
            scal[6+3*h]=e0/s; scal[7+3*h]=e1/s; scal[8+3*h]=e2/s;
            scal[4+h] = 1.f + splus(ps[5]);
        }
        __syncthreads();

        // ---- G: key norm + content softmax + interp + shift + sharpen ----
        if (t < 128){
            const int h = t>>6, l = ln;
            float kvl = kv[h][l];
            float kn2 = kvl*kvl;
            for (int off=32; off>=1; off>>=1) kn2 += __shfl_xor(kn2, off);
            float kn = sqrtf(kn2);
            float beta = scal[h], g = scal[2+h];
            float bk0 = beta * innr[h][l]   /(kn*Mn[l]   +1e-8f);
            float bk1 = beta * innr[h][l+64]/(kn*Mn[l+64]+1e-8f);
            float mx = fmaxf(bk0,bk1);
            for (int off=32; off>=1; off>>=1) mx = fmaxf(mx, __shfl_xor(mx, off));
            float e0=__expf(bk0-mx), e1=__expf(bk1-mx);
            float s=e0+e1;
            for (int off=32; off>=1; off>>=1) s += __shfl_xor(s, off);
            float wc0=e0/s, wc1=e1/s;
            wgs[h][l]    = g*wc0 + (1.f-g)*wtab[h][l];
            wgs[h][l+64] = g*wc1 + (1.f-g)*wtab[h][l+64];
            float gamma = scal[4+h];
            float s0=scal[6+3*h], s1=scal[7+3*h], s2=scal[8+3*h];
            const int n0=l, n1=l+64;
            float wt0 = s0*wgs[h][(n0+1)&127] + s1*wgs[h][n0] + s2*wgs[h][(n0+127)&127];
            float wt1 = s0*wgs[h][(n1+1)&127] + s1*wgs[h][n1] + s2*wgs[h][(n1+127)&127];
            float wp0 = __powf(wt0, gamma), wp1 = __powf(wt1, gamma);
            float ss = wp0+wp1;
            for (int off=32; off>=1; off>>=1) ss += __shfl_xor(ss, off);
            float inv = 1.0f/(ss+1e-8f);
            wtab[h][n0] = wp0*inv; wtab[h][n1] = wp1*inv;
        }
        __syncthreads();

        // ---- H: memory write + fused read-head partials ----
        {
            const float el = ebuf[ln], al = abuf[ln];
            const int n0 = wv*8;
            float racc = 0.f;
            #pragma unroll
            for (int k=0; k<8; ++k){
                const int n = n0+k;
                float ww = wtab[1][n];
                float wr = wtab[0][n];
                float v = Mem[n][ln]*(1.0f - ww*el) + ww*al;
                Mem[n][ln] = v;
                racc = fmaf(wr, v, racc);
            }
            rpart[wv][ln] = racc;
        }
        __syncthreads();

        // ---- J: r finalize + output (hf==0 writes) + xr2 r-pack ----
        if (t < 512){
            const int o = wv;
            float rm = 0.f;
            #pragma unroll
            for (int k=0; k<16; ++k) rm += rpart[k][ln];
            float s = rm * W_o[(U_+ln)*OUT_ + o];
            for (int off=32; off>=1; off>>=1) s += __shfl_xor(s, off);
            if (ln==0 && hf==0 && step>=TSTART){
                float logit = clipf(s + jpart[o] + b_o[o]);
                out[((b*(T_-TSTART)) + (step-TSTART))*OUT_ + o] = sigf(logit);
            }
        } else if (t < 576){
            float rm = 0.f;
            #pragma unroll
            for (int k=0; k<16; ++k) rm += rpart[k][ln];
            float other = __shfl_xor(rm, 1);
            if (!(ln&1)){
                h2_t v; v.x = (_Float16)rm; v.y = (_Float16)other;
                xr2[ln>>1] = v;
            }
        }
        __syncthreads();
    }
}

extern "C" void kernel_launch(void* const* d_in, const int* in_sizes, int n_in,
                              void* d_out, int out_size, void* d_ws, size_t ws_size,
                              hipStream_t stream) {
    const float* inputs = (const float*)d_in[0];
    const float* W_x    = (const float*)d_in[1];
    const float* W_h    = (const float*)d_in[2];
    const float* b_lstm = (const float*)d_in[3];
    const float* W_p    = (const float*)d_in[4];
    const float* b_p    = (const float*)d_in[5];
    const float* W_o    = (const float*)d_in[6];
    const float* b_o    = (const float*)d_in[7];
    const float* r0     = (const float*)d_in[8];
    const float* w0     = (const float*)d_in[9];
    float* out = (float*)d_out;

    char* ws = (char*)d_ws;
    uint4*  wx2 = (uint4*)(ws + WX2_OFF);
    uint4*  wh2 = (uint4*)(ws + WHG_OFF);
    uint4*  wp2 = (uint4*)(ws + WPG_OFF);
    float4* blh = (float4*)(ws + BLH_OFF);
    float*  bpp = (float*)(ws + BPP_OFF);
    char*   comm = ws + COMM_OFF;

    hipMemsetAsync(comm, 0, COMM_SZ, stream);
    prep_kernel<<<512, 256, 0, stream>>>(W_x, W_h, W_p, b_lstm, b_p, wx2, wh2, wp2, blh, bpp);
    ntm_kernel<<<2*B_, 1024, 0, stream>>>(inputs, W_o, b_o, r0, w0,
                                          wx2, wh2, wp2, blh, bpp, comm, out);
}

// Round 15
// 2105.694 us; speedup vs baseline: 1.4312x; 1.0811x over previous
//
#include <hip/hip_runtime.h>
#include <math.h>

typedef _Float16 h2_t __attribute__((ext_vector_type(2)));

#define U_ 256
#define NN 128
#define MM 64
#define OUT_ 8
#define CLIPV 20.0f
#define IN_DIM_ 9
#define PP 268
#define B_ 128
#define T_ 130
#define TSTART 65

// ws element counts / byte offsets
#define NWX2 10240      // 2hf * 16wv * 5p * 64ln        (uint4, conflict-free pinned)
#define NWHG 32768      // 2hf * 128g4 * 128slot(p*8+q)  (uint4, kk=q*16+p)
#define NWPG 8704       // 2hf * 34cg * 128slot(p*8+q)   (uint4, kk=q*16+p)
#define WX2_OFF 0
#define WHG_OFF 163840
#define WPG_OFF 688128
#define BLH_OFF 827392
#define BPP_OFF 831488
#define COMM_OFF 832640
#define COMM_STRIDE 2176          // hA512|hB512|pA544|pB544|flags|pad
#define COMM_SZ (B_*COMM_STRIDE)
#define PREP_N (NWX2 + NWHG + NWPG + 256 + 272)

__device__ __forceinline__ float sigf(float x){ return 1.0f/(1.0f+__expf(-x)); }
__device__ __forceinline__ float splus(float x){ return log1pf(__expf(x)); }
__device__ __forceinline__ float clipf(float x){ return fminf(fmaxf(x,-CLIPV),CLIPV); }

#if defined(__has_builtin)
#if __has_builtin(__builtin_amdgcn_fdot2)
#define DOT2(a,b,c) __builtin_amdgcn_fdot2((a),(b),(c),false)
#endif
#endif
#ifndef DOT2
#define DOT2(a,b,c) fmaf((float)(a).x,(float)(b).x, fmaf((float)(a).y,(float)(b).y,(c)))
#endif

#define DOT2X4(uu, hv) { \
    a0 = DOT2(hv, __builtin_bit_cast(h2_t,(uu).x), a0); \
    a1 = DOT2(hv, __builtin_bit_cast(h2_t,(uu).y), a1); \
    a2 = DOT2(hv, __builtin_bit_cast(h2_t,(uu).z), a2); \
    a3 = DOT2(hv, __builtin_bit_cast(h2_t,(uu).w), a3); }
#define DOT2P(uu, hv) { \
    pa0 = DOT2(hv, __builtin_bit_cast(h2_t,(uu).x), pa0); \
    pa1 = DOT2(hv, __builtin_bit_cast(h2_t,(uu).y), pa1); \
    pa2 = DOT2(hv, __builtin_bit_cast(h2_t,(uu).z), pa2); \
    pa3 = DOT2(hv, __builtin_bit_cast(h2_t,(uu).w), pa3); }
#define H2C(hu) __builtin_bit_cast(h2_t,(hu))

__device__ __forceinline__ unsigned packh2(float a, float b){
    h2_t v; v.x = (_Float16)a; v.y = (_Float16)b;
    return __builtin_bit_cast(unsigned, v);
}

__global__ void prep_kernel(const float* __restrict__ W_x, const float* __restrict__ W_h,
                            const float* __restrict__ W_p, const float* __restrict__ b_lstm,
                            const float* __restrict__ b_p,
                            uint4* __restrict__ wx2, uint4* __restrict__ wh2,
                            uint4* __restrict__ wp2,
                            float4* __restrict__ blh, float* __restrict__ bpp)
{
    for (int idx = blockIdx.x*blockDim.x + threadIdx.x; idx < PREP_N; idx += gridDim.x*blockDim.x){
        if (idx < NWX2){
            // conflict-free pinned layout: [hf][wv][p][ln]
            int hf = idx/5120, rem = idx - hf*5120;
            int wv = rem/320, r2 = rem - wv*320, p = r2>>6, ln = r2&63;
            int g4 = wv*8 + (ln>>3), q = ln&7, kk = q*5+p;
            int k0 = 2*kk, k1 = k0+1;
            unsigned c[4];
            #pragma unroll
            for (int g=0; g<4; ++g){
                int col = g*256 + hf*128 + g4;
                float f0 = (k0<64) ? W_x[(9+k0)*1024+col] : (k0<73 ? W_x[(k0-64)*1024+col] : 0.f);
                float f1 = (k1<64) ? W_x[(9+k1)*1024+col] : (k1<73 ? W_x[(k1-64)*1024+col] : 0.f);
                c[g] = packh2(f0,f1);
            }
            wx2[idx] = make_uint4(c[0],c[1],c[2],c[3]);
        } else if (idx < NWX2 + NWHG){
            int e = idx - NWX2;
            int hf = e>>14, rem = e&16383, g4 = rem>>7, s = rem&127;
            int p = s>>3, q = s&7, kk = q*16+p;
            unsigned c[4];
            #pragma unroll
            for (int g=0; g<4; ++g){
                int col = g*256 + hf*128 + g4;
                c[g] = packh2(W_h[(2*kk)*1024+col], W_h[(2*kk+1)*1024+col]);
            }
            wh2[e] = make_uint4(c[0],c[1],c[2],c[3]);
        } else if (idx < NWX2 + NWHG + NWPG){
            int e = idx - NWX2 - NWHG;
            int hf = e/4352, rem = e - hf*4352, cg = rem>>7, s = rem&127;
            int p = s>>3, q = s&7, kk = q*16+p;
            unsigned c[4];
            #pragma unroll
            for (int g=0; g<4; ++g){
                int cl = cg*4+g, rc = hf*134+cl;
                c[g] = (cl<134) ? packh2(W_p[(2*kk)*PP+rc], W_p[(2*kk+1)*PP+rc]) : 0u;
            }
            wp2[e] = make_uint4(c[0],c[1],c[2],c[3]);
        } else if (idx < NWX2 + NWHG + NWPG + 256){
            int u = idx - NWX2 - NWHG - NWPG;
            blh[u] = make_float4(b_lstm[u], b_lstm[256+u], b_lstm[512+u], b_lstm[768+u]);
        } else {
            int j = idx - NWX2 - NWHG - NWPG - 256;
            bpp[j] = (j < PP) ? b_p[j] : 0.f;
        }
    }
}

__device__ __forceinline__ float decodeP(int rc, float p){
    if (rc < 64 || (rc >= 70 && rc < 134) || rc >= 204) return tanhf(p);
    if (rc >= 140 && rc < 204) return sigf(p);
    return p;
}

__global__ __launch_bounds__(1024,1) void ntm_kernel(
    const float* __restrict__ inputs,
    const float* __restrict__ W_o, const float* __restrict__ b_o,
    const float* __restrict__ r0, const float* __restrict__ w0,
    const uint4* __restrict__ wx2, const uint4* __restrict__ whg,
    const uint4* __restrict__ wpg,
    const float4* __restrict__ blh, const float* __restrict__ bpp,
    char* comm, float* __restrict__ out)
{
    const int bid = blockIdx.x, hf = bid>>7, b = bid&127;
    const int t = threadIdx.x, wv = t>>6, ln = t&63;
    const int g4 = t>>3, q = t&7;

    char* cb = comm + b*COMM_STRIDE;
    volatile float* hOwn = (volatile float*)(cb + hf*512);
    volatile float* hOth = (volatile float*)(cb + (hf^1)*512);
    volatile float* pOwn = (volatile float*)(cb + 1024 + hf*544);
    volatile float* pOth = (volatile float*)(cb + 1024 + (hf^1)*544);
    volatile int*   flg  = (volatile int*)(cb + 2112);   // [f1A,f1B,f2A,f2B]

    __shared__ uint4 wxL[5120];          // 80KB pinned W_x half (conflict-free)
    __shared__ uint4 whL[2][1024];       // 32KB pinned W_h slices p=0,1 (index = [p][t])
    __shared__ float Mem[NN][MM+1];
    __shared__ float4 gpart4[128];
    __shared__ float4 blhL[128];
    __shared__ float hbuf[U_];
    __shared__ float cbuf[128];
    __shared__ h2_t  hb2[128] __attribute__((aligned(16)));
    __shared__ h2_t  xr2[40] __attribute__((aligned(16)));
    __shared__ float prmS[12];
    __shared__ float scal[12];
    __shared__ float kv[2][MM], ebuf[MM], abuf[MM];
    __shared__ float innr[2][NN], Mn[NN], wgs[2][NN], wtab[2][NN];
    __shared__ float rpart[16][MM];
    __shared__ float jpart[OUT_];

    // ---- init ----
    for (int i=t; i<5120; i+=1024) wxL[i] = wx2[hf*5120 + i];
    for (int i=t; i<2048; i+=1024){
        int p = i>>10, j = i&1023;
        whL[p][j] = whg[hf*16384 + (j>>3)*128 + p*8 + (j&7)];
    }
    for (int i=t; i<NN*MM; i+=1024) Mem[i>>6][i&63] = 1e-6f;
    if (t < 128){
        gpart4[t] = make_float4(0.f,0.f,0.f,0.f);
        blhL[t] = blh[hf*128+t];
        cbuf[t] = 0.f;
        Mn[t] = 8e-6f;
        h2_t z; z.x=(_Float16)0.f; z.y=(_Float16)0.f; hb2[t] = z;
    }
    if (t < U_) hbuf[t] = 0.f;
    if (t >= 128 && t < 256){  // wtab = softmax(w0)
        int h = (t-128)>>6, l = t&63;
        float v0 = w0[h*NN + l], v1 = w0[h*NN + l + 64];
        float mx = fmaxf(v0,v1);
        for (int off=32; off>=1; off>>=1) mx = fmaxf(mx, __shfl_xor(mx, off));
        float e0 = __expf(v0-mx), e1 = __expf(v1-mx);
        float s = e0+e1;
        for (int off=32; off>=1; off>>=1) s += __shfl_xor(s, off);
        wtab[h][l] = e0/s; wtab[h][l+64] = e1/s;
    }
    if (t >= 256 && t < 296){
        int p = t-256;
        h2_t v;
        if (p < 32){ v.x = (_Float16)tanhf(r0[2*p]); v.y = (_Float16)tanhf(r0[2*p+1]); }
        else if (p < 37){
            int e0 = 2*(p-32), e1 = e0+1;
            float f0 = (e0<IN_DIM_) ? inputs[b*T_*IN_DIM_ + e0] : 0.f;
            float f1 = (e1<IN_DIM_) ? inputs[b*T_*IN_DIM_ + e1] : 0.f;
            v.x = (_Float16)f0; v.y = (_Float16)f1;
        } else { v.x=(_Float16)0.f; v.y=(_Float16)0.f; }
        xr2[p] = v;
    }
    __syncthreads();

    for (int step=0; step<T_; ++step){
        // ---- B: gates from pinned wx (conflict-free) + gpart + bias, fused LSTM ----
        {
            const uint4* wb = wxL + wv*320;
            float a0=0.f,a1=0.f,a2=0.f,a3=0.f;
            #pragma unroll
            for (int p=0; p<5; ++p){
                uint4 u = wb[p*64 + ln];
                h2_t xv = xr2[q*5+p];
                DOT2X4(u, xv);
            }
            #pragma unroll
            for (int m=1; m<8; m<<=1){
                a0 += __shfl_xor(a0,m); a1 += __shfl_xor(a1,m);
                a2 += __shfl_xor(a2,m); a3 += __shfl_xor(a3,m);
            }
            if (q==0){
                float4 bb = blhL[g4]; float4 gp = gpart4[g4];
                float gi=a0+bb.x+gp.x, gf=a1+bb.y+gp.y, gg=a2+bb.z+gp.z, go=a3+bb.w+gp.w;
                float c = sigf(gf)*cbuf[g4] + sigf(gi)*tanhf(gg);
                cbuf[g4] = c;
                float h = sigf(go)*tanhf(c);
                hbuf[hf*128+g4] = h;
                hOwn[g4] = h;
            }
        }
        __syncthreads();                          // drains volatile h stores
        if (t==0){
            flg[hf] = step+1;
            while (flg[hf^1] < step+1) __builtin_amdgcn_s_sleep(8);
        }
        __syncthreads();
        // pull partner h; build fp16 h pairs
        if (t < 128){
            float hv = hOth[t];
            hbuf[(hf^1)*128 + t] = hv;
            float hv2 = __shfl_down(hv, 1);
            if (!(t&1)){ h2_t vv; vv.x=(_Float16)hv; vv.y=(_Float16)hv2; hb2[(hf^1)*64 + (t>>1)] = vv; }
        } else if (t < 192){
            int jj = t-128;
            h2_t vv; vv.x=(_Float16)hbuf[hf*128+2*jj]; vv.y=(_Float16)hbuf[hf*128+2*jj+1];
            hb2[hf*64+jj] = vv;
        }
        __syncthreads();

        const uint4* hb2q = (const uint4*)hb2;

        // ---- FUSED: gpart (all threads, 8-deep; p=0,1 from LDS) ; wp ; Mn ; jpart ; x-pre ----
        {
            const uint4* wrow = whg + hf*16384 + g4*128;
            uint4 hA = hb2q[q*4+0], hB = hb2q[q*4+1], hC = hb2q[q*4+2], hD = hb2q[q*4+3];
            float a0=0.f,a1=0.f,a2=0.f,a3=0.f;
            {
                uint4 u0=whL[0][t], u1=whL[1][t];
                uint4 u2=wrow[2*8+q], u3=wrow[3*8+q];
                uint4 u4=wrow[4*8+q], u5=wrow[5*8+q], u6=wrow[6*8+q], u7=wrow[7*8+q];
                DOT2X4(u0, H2C(hA.x)); DOT2X4(u1, H2C(hA.y));
                DOT2X4(u2, H2C(hA.z)); DOT2X4(u3, H2C(hA.w));
                DOT2X4(u4, H2C(hB.x)); DOT2X4(u5, H2C(hB.y));
                DOT2X4(u6, H2C(hB.z)); DOT2X4(u7, H2C(hB.w));
            }
            {
                uint4 u0=wrow[8*8+q],  u1=wrow[9*8+q],  u2=wrow[10*8+q], u3=wrow[11*8+q];
                uint4 u4=wrow[12*8+q], u5=wrow[13*8+q], u6=wrow[14*8+q], u7=wrow[15*8+q];
                DOT2X4(u0, H2C(hC.x)); DOT2X4(u1, H2C(hC.y));
                DOT2X4(u2, H2C(hC.z)); DOT2X4(u3, H2C(hC.w));
                DOT2X4(u4, H2C(hD.x)); DOT2X4(u5, H2C(hD.y));
                DOT2X4(u6, H2C(hD.z)); DOT2X4(u7, H2C(hD.w));
            }
            #pragma unroll
            for (int m=1; m<8; m<<=1){
                a0 += __shfl_xor(a0,m); a1 += __shfl_xor(a1,m);
                a2 += __shfl_xor(a2,m); a3 += __shfl_xor(a3,m);
            }
            if (q==0) gpart4[g4] = make_float4(a0,a1,a2,a3);
        }
        if (t < 272){
            const int cg = t>>3, qq = t&7;
            const uint4* wrow = wpg + (hf*34+cg)*128;
            uint4 hA = hb2q[qq*4+0], hB = hb2q[qq*4+1], hC = hb2q[qq*4+2], hD = hb2q[qq*4+3];
            float pa0=0.f, pa1=0.f, pa2=0.f, pa3=0.f;
            {
                uint4 u0=wrow[0*8+qq], u1=wrow[1*8+qq], u2=wrow[2*8+qq], u3=wrow[3*8+qq];
                uint4 u4=wrow[4*8+qq], u5=wrow[5*8+qq], u6=wrow[6*8+qq], u7=wrow[7*8+qq];
                DOT2P(u0, H2C(hA.x)); DOT2P(u1, H2C(hA.y));
                DOT2P(u2, H2C(hA.z)); DOT2P(u3, H2C(hA.w));
                DOT2P(u4, H2C(hB.x)); DOT2P(u5, H2C(hB.y));
                DOT2P(u6, H2C(hB.z)); DOT2P(u7, H2C(hB.w));
            }
            {
                uint4 u0=wrow[8*8+qq],  u1=wrow[9*8+qq],  u2=wrow[10*8+qq], u3=wrow[11*8+qq];
                uint4 u4=wrow[12*8+qq], u5=wrow[13*8+qq], u6=wrow[14*8+qq], u7=wrow[15*8+qq];
                DOT2P(u0, H2C(hC.x)); DOT2P(u1, H2C(hC.y));
                DOT2P(u2, H2C(hC.z)); DOT2P(u3, H2C(hC.w));
                DOT2P(u4, H2C(hD.x)); DOT2P(u5, H2C(hD.y));
                DOT2P(u6, H2C(hD.z)); DOT2P(u7, H2C(hD.w));
            }
            #pragma unroll
            for (int m=1; m<8; m<<=1){
                pa0 += __shfl_xor(pa0,m); pa1 += __shfl_xor(pa1,m);
                pa2 += __shfl_xor(pa2,m); pa3 += __shfl_xor(pa3,m);
            }
            if (qq==0){
                #pragma unroll
                for (int j=0; j<4; ++j){
                    float aj = (j==0)?pa0:((j==1)?pa1:((j==2)?pa2:pa3));
                    int cl = cg*4+j;
                    if (cl < 134){
                        int rc = hf*134+cl;
                        float pv = clipf(aj + bpp[rc]);
                        float dv = decodeP(rc, pv);
                        pOwn[cl] = dv;
                        if (rc < 64) kv[0][rc] = dv;
                        else if (rc < 70) prmS[rc-64] = dv;
                        else if (rc < 134) kv[1][rc-70] = dv;
                        else if (rc < 140) prmS[6+rc-134] = dv;
                        else if (rc < 204) ebuf[rc-140] = dv;
                        else abuf[rc-204] = dv;
                    }
                }
            }
        } else if (t < 528){
            const int idx = t-272, n = idx>>1, m0 = (idx&1)*32;
            float s = 0.f;
            #pragma unroll 8
            for (int m=m0; m<m0+32; ++m){ float v=Mem[n][m]; s=fmaf(v,v,s); }
            s += __shfl_xor(s,1);
            if (!(idx&1)) Mn[n] = sqrtf(s);
        } else if (t < 656){
            const int o = (t-528)>>4, l16 = (t-528)&15;
            float s = 0.f;
            #pragma unroll
            for (int j=0; j<16; ++j){
                const int i = l16 + (j<<4);
                s = fmaf(hbuf[i], W_o[i*OUT_ + o], s);
            }
            s += __shfl_xor(s,1); s += __shfl_xor(s,2);
            s += __shfl_xor(s,4); s += __shfl_xor(s,8);
            if (l16==0) jpart[o] = s;
        } else if (t >= 656 && t < 661){
            if (step+1 < T_){
                const int p = t-656;
                const int e0 = 2*p, e1 = e0+1;
                const float* xin = inputs + (b*T_ + step+1)*IN_DIM_;
                h2_t v;
                v.x = (_Float16)((e0<IN_DIM_) ? xin[e0] : 0.f);
                v.y = (_Float16)((e1<IN_DIM_) ? xin[e1] : 0.f);
                xr2[32+p] = v;
            }
        }
        __syncthreads();                          // drains volatile p stores
        if (t==0){
            flg[2+hf] = step+1;
            while (flg[2+(hf^1)] < step+1) __builtin_amdgcn_s_sleep(8);
        }
        __syncthreads();
        if (t < 134){                              // route partner's decoded params
            float dv = pOth[t];
            int rc = (hf^1)*134 + t;
            if (rc < 64) kv[0][rc] = dv;
            else if (rc < 70) prmS[rc-64] = dv;
            else if (rc < 134) kv[1][rc-70] = dv;
            else if (rc < 140) prmS[6+rc-134] = dv;
            else if (rc < 204) ebuf[rc-140] = dv;
            else abuf[rc-204] = dv;
        }
        __syncthreads();

        // ---- F: inner products + scal decode ----
        {
            const int h = t>>9, n = (t>>2)&127, qm = t&3, m0 = qm*16;
            float s = 0.f;
            #pragma unroll 8
            for (int m=m0; m<m0+16; ++m) s = fmaf(kv[h][m], Mem[n][m], s);
            s += __shfl_xor(s,1); s += __shfl_xor(s,2);
            if (qm==0) innr[h][n] = s;
        }
        if (t < 2){
            const int h = t;
            const float* ps = prmS + 6*h;
            scal[h]   = splus(ps[0]);
            scal[2+h] = sigf(ps[1]);
            float p0=ps[2], p1=ps[3], p2=ps[4];
            float mx = fmaxf(p0, fmaxf(p1, p2));
            float e0=__expf(p0-mx), e1=__expf(p1-mx), e2=__expf(p2-mx);
            float s = e0+e1+e2;
            scal[6+3*h]=e0/s; scal[7+3*h]=e1/s; scal[8+3*h]=e2/s;
            scal[4+h] = 1.f + splus(ps[5]);
        }
        __syncthreads();

        // ---- G: key norm + content softmax + interp + shift + sharpen ----
        if (t < 128){
            const int h = t>>6, l = ln;
            float kvl = kv[h][l];
            float kn2 = kvl*kvl;
            for (int off=32; off>=1; off>>=1) kn2 += __shfl_xor(kn2, off);
            float kn = sqrtf(kn2);
            float beta = scal[h], g = scal[2+h];
            float bk0 = beta * innr[h][l]   /(kn*Mn[l]   +1e-8f);
            float bk1 = beta * innr[h][l+64]/(kn*Mn[l+64]+1e-8f);
            float mx = fmaxf(bk0,bk1);
            for (int off=32; off>=1; off>>=1) mx = fmaxf(mx, __shfl_xor(mx, off));
            float e0=__expf(bk0-mx), e1=__expf(bk1-mx);
            float s=e0+e1;
            for (int off=32; off>=1; off>>=1) s += __shfl_xor(s, off);
            float wc0=e0/s, wc1=e1/s;
            wgs[h][l]    = g*wc0 + (1.f-g)*wtab[h][l];
            wgs[h][l+64] = g*wc1 + (1.f-g)*wtab[h][l+64];
            float gamma = scal[4+h];
            float s0=scal[6+3*h], s1=scal[7+3*h], s2=scal[8+3*h];
            const int n0=l, n1=l+64;
            float wt0 = s0*wgs[h][(n0+1)&127] + s1*wgs[h][n0] + s2*wgs[h][(n0+127)&127];
            float wt1 = s0*wgs[h][(n1+1)&127] + s1*wgs[h][n1] + s2*wgs[h][(n1+127)&127];
            float wp0 = __powf(wt0, gamma), wp1 = __powf(wt1, gamma);
            float ss = wp0+wp1;
            for (int off=32; off>=1; off>>=1) ss += __shfl_xor(ss, off);
            float inv = 1.0f/(ss+1e-8f);
            wtab[h][n0] = wp0*inv; wtab[h][n1] = wp1*inv;
        }
        __syncthreads();

        // ---- H: memory write + fused read-head partials ----
        {
            const float el = ebuf[ln], al = abuf[ln];
            const int n0 = wv*8;
            float racc = 0.f;
            #pragma unroll
            for (int k=0; k<8; ++k){
                const int n = n0+k;
                float ww = wtab[1][n];
                float wr = wtab[0][n];
                float v = Mem[n][ln]*(1.0f - ww*el) + ww*al;
                Mem[n][ln] = v;
                racc = fmaf(wr, v, racc);
            }
            rpart[wv][ln] = racc;
        }
        __syncthreads();

        // ---- J: r finalize + output (hf==0 writes) + xr2 r-pack ----
        if (t < 512){
            const int o = wv;
            float rm = 0.f;
            #pragma unroll
            for (int k=0; k<16; ++k) rm += rpart[k][ln];
            float s = rm * W_o[(U_+ln)*OUT_ + o];
            for (int off=32; off>=1; off>>=1) s += __shfl_xor(s, off);
            if (ln==0 && hf==0 && step>=TSTART){
                float logit = clipf(s + jpart[o] + b_o[o]);
                out[((b*(T_-TSTART)) + (step-TSTART))*OUT_ + o] = sigf(logit);
            }
        } else if (t < 576){
            float rm = 0.f;
            #pragma unroll
            for (int k=0; k<16; ++k) rm += rpart[k][ln];
            float other = __shfl_xor(rm, 1);
            if (!(ln&1)){
                h2_t v; v.x = (_Float16)rm; v.y = (_Float16)other;
                xr2[ln>>1] = v;
            }
        }
        __syncthreads();
    }
}

extern "C" void kernel_launch(void* const* d_in, const int* in_sizes, int n_in,
                              void* d_out, int out_size, void* d_ws, size_t ws_size,
                              hipStream_t stream) {
    const float* inputs = (const float*)d_in[0];
    const float* W_x    = (const float*)d_in[1];
    const float* W_h    = (const float*)d_in[2];
    const float* b_lstm = (const float*)d_in[3];
    const float* W_p    = (const float*)d_in[4];
    const float* b_p    = (const float*)d_in[5];
    const float* W_o    = (const float*)d_in[6];
    const float* b_o    = (const float*)d_in[7];
    const float* r0     = (const float*)d_in[8];
    const float* w0     = (const float*)d_in[9];
    float* out = (float*)d_out;

    char* ws = (char*)d_ws;
    uint4*  wx2 = (uint4*)(ws + WX2_OFF);
    uint4*  wh2 = (uint4*)(ws + WHG_OFF);
    uint4*  wp2 = (uint4*)(ws + WPG_OFF);
    float4* blh = (float4*)(ws + BLH_OFF);
    float*  bpp = (float*)(ws + BPP_OFF);
    char*   comm = ws + COMM_OFF;

    hipMemsetAsync(comm, 0, COMM_SZ, stream);
    prep_kernel<<<512, 256, 0, stream>>>(W_x, W_h, W_p, b_lstm, b_p, wx2, wh2, wp2, blh, bpp);
    ntm_kernel<<<2*B_, 1024, 0, stream>>>(inputs, W_o, b_o, r0, w0,
                                          wx2, wh2, wp2, blh, bpp, comm, out);
}

// Round 16
// 2089.940 us; speedup vs baseline: 1.4419x; 1.0075x over previous
//
#include <hip/hip_runtime.h>
#include <math.h>

typedef _Float16 h2_t __attribute__((ext_vector_type(2)));

#define U_ 256
#define NN 128
#define MM 64
#define OUT_ 8
#define CLIPV 20.0f
#define IN_DIM_ 9
#define PP 268
#define B_ 128
#define T_ 130
#define TSTART 65

// ws element counts / byte offsets
#define NWX2 10240      // 2hf * 16wv * 5p * 64ln      (uint4 fp16, conflict-free pinned)
#define NWH8 16384      // 2hf * 128g4 * 64slot(j*8+q) (uint4 = 16 fp8: 4col x 4k)
#define NWPG 8704       // 2hf * 34cg * 128slot(p*8+q) (uint4 fp16, kk=q*16+p)
#define WX2_OFF 0
#define WH8_OFF 163840
#define WPG_OFF 425984
#define BLH_OFF 565248
#define BPP_OFF 569344
#define COMM_OFF 570432
#define COMM_STRIDE 2176          // hA512|hB512|pA544|pB544|flags|pad
#define COMM_SZ (B_*COMM_STRIDE)
#define PREP_N (NWX2 + NWH8 + NWPG + 256 + 272)

__device__ __forceinline__ float sigf(float x){ return 1.0f/(1.0f+__expf(-x)); }
__device__ __forceinline__ float splus(float x){ return log1pf(__expf(x)); }
__device__ __forceinline__ float clipf(float x){ return fminf(fmaxf(x,-CLIPV),CLIPV); }

#if defined(__has_builtin)
#if __has_builtin(__builtin_amdgcn_fdot2)
#define DOT2(a,b,c) __builtin_amdgcn_fdot2((a),(b),(c),false)
#endif
#endif
#ifndef DOT2
#define DOT2(a,b,c) fmaf((float)(a).x,(float)(b).x, fmaf((float)(a).y,(float)(b).y,(c)))
#endif

#define DOT2X4(uu, hv) { \
    a0 = DOT2(hv, __builtin_bit_cast(h2_t,(uu).x), a0); \
    a1 = DOT2(hv, __builtin_bit_cast(h2_t,(uu).y), a1); \
    a2 = DOT2(hv, __builtin_bit_cast(h2_t,(uu).z), a2); \
    a3 = DOT2(hv, __builtin_bit_cast(h2_t,(uu).w), a3); }
#define DOT2P(uu, hv) { \
    pa0 = DOT2(hv, __builtin_bit_cast(h2_t,(uu).x), pa0); \
    pa1 = DOT2(hv, __builtin_bit_cast(h2_t,(uu).y), pa1); \
    pa2 = DOT2(hv, __builtin_bit_cast(h2_t,(uu).z), pa2); \
    pa3 = DOT2(hv, __builtin_bit_cast(h2_t,(uu).w), pa3); }
#define H2C(hu) __builtin_bit_cast(h2_t,(hu))

// fp8 e4m3 decode: word = bytes [k0,k2,k1,k3]; outA = h2(k0,k1), outB = h2(k2,k3),
// each fp16 value = stored_value/256 (we fold x256/16prescale = x16 into final store).
#define DEC1(vv, aa, hX, hY) { \
    unsigned oA = (((vv)<<7)&0x3F803F80u)|(((vv)<<8)&0x80008000u); \
    unsigned oB = (((vv)>>1)&0x3F803F80u)|((vv)&0x80008000u); \
    aa = DOT2(hX, H2C(oA), aa); aa = DOT2(hY, H2C(oB), aa); }
#define DEC8(u, hX, hY) { \
    DEC1((u).x, a0, hX, hY); DEC1((u).y, a1, hX, hY); \
    DEC1((u).z, a2, hX, hY); DEC1((u).w, a3, hX, hY); }

__device__ __forceinline__ unsigned packh2(float a, float b){
    h2_t v; v.x = (_Float16)a; v.y = (_Float16)b;
    return __builtin_bit_cast(unsigned, v);
}

// encode w -> e4m3 byte of (w*16): via fp16(w/16) bits >> 7, RTNE
__device__ __forceinline__ unsigned enc8(float w){
    _Float16 h = (_Float16)(w * 0.0625f);
    unsigned short hb = __builtin_bit_cast(unsigned short, h);
    unsigned s = ((unsigned)hb >> 8) & 0x80u;
    unsigned mag = (unsigned)hb & 0x7FFFu;
    unsigned b = (mag + 0x3Fu + ((mag>>7)&1u)) >> 7;
    if (b > 0x7Fu) b = 0x7Fu;
    return s | b;
}

__global__ void prep_kernel(const float* __restrict__ W_x, const float* __restrict__ W_h,
                            const float* __restrict__ W_p, const float* __restrict__ b_lstm,
                            const float* __restrict__ b_p,
                            uint4* __restrict__ wx2, uint4* __restrict__ whf8,
                            uint4* __restrict__ wp2,
                            float4* __restrict__ blh, float* __restrict__ bpp)
{
    for (int idx = blockIdx.x*blockDim.x + threadIdx.x; idx < PREP_N; idx += gridDim.x*blockDim.x){
        if (idx < NWX2){
            // conflict-free pinned layout: [hf][wv][p][ln]
            int hf = idx/5120, rem = idx - hf*5120;
            int wv = rem/320, r2 = rem - wv*320, p = r2>>6, ln = r2&63;
            int g4 = wv*8 + (ln>>3), q = ln&7, kk = q*5+p;
            int k0 = 2*kk, k1 = k0+1;
            unsigned c[4];
            #pragma unroll
            for (int g=0; g<4; ++g){
                int col = g*256 + hf*128 + g4;
                float f0 = (k0<64) ? W_x[(9+k0)*1024+col] : (k0<73 ? W_x[(k0-64)*1024+col] : 0.f);
                float f1 = (k1<64) ? W_x[(9+k1)*1024+col] : (k1<73 ? W_x[(k1-64)*1024+col] : 0.f);
                c[g] = packh2(f0,f1);
            }
            wx2[idx] = make_uint4(c[0],c[1],c[2],c[3]);
        } else if (idx < NWX2 + NWH8){
            // fp8 W_h: [hf][g4][slot j*8+q]; word g = col(g)'s k-values [k0,k2,k1,k3], kbase=q*32+4j
            int e = idx - NWX2;
            int hf = e>>13, rem = e&8191, g4 = rem>>6, s = rem&63;
            int j = s>>3, q = s&7, kb = q*32 + 4*j;
            unsigned c[4];
            #pragma unroll
            for (int g=0; g<4; ++g){
                int col = g*256 + hf*128 + g4;
                unsigned b0 = enc8(W_h[(kb+0)*1024+col]);
                unsigned b1 = enc8(W_h[(kb+2)*1024+col]);
                unsigned b2 = enc8(W_h[(kb+1)*1024+col]);
                unsigned b3 = enc8(W_h[(kb+3)*1024+col]);
                c[g] = b0 | (b1<<8) | (b2<<16) | (b3<<24);
            }
            whf8[e] = make_uint4(c[0],c[1],c[2],c[3]);
        } else if (idx < NWX2 + NWH8 + NWPG){
            int e = idx - NWX2 - NWH8;
            int hf = e/4352, rem = e - hf*4352, cg = rem>>7, s = rem&127;
            int p = s>>3, q = s&7, kk = q*16+p;
            unsigned c[4];
            #pragma unroll
            for (int g=0; g<4; ++g){
                int cl = cg*4+g, rc = hf*134+cl;
                c[g] = (cl<134) ? packh2(W_p[(2*kk)*PP+rc], W_p[(2*kk+1)*PP+rc]) : 0u;
            }
            wp2[e] = make_uint4(c[0],c[1],c[2],c[3]);
        } else if (idx < NWX2 + NWH8 + NWPG + 256){
            int u = idx - NWX2 - NWH8 - NWPG;
            blh[u] = make_float4(b_lstm[u], b_lstm[256+u], b_lstm[512+u], b_lstm[768+u]);
        } else {
            int j = idx - NWX2 - NWH8 - NWPG - 256;
            bpp[j] = (j < PP) ? b_p[j] : 0.f;
        }
    }
}

__device__ __forceinline__ float decodeP(int rc, float p){
    if (rc < 64 || (rc >= 70 && rc < 134) || rc >= 204) return tanhf(p);
    if (rc >= 140 && rc < 204) return sigf(p);
    return p;
}

__global__ __launch_bounds__(1024,1) void ntm_kernel(
    const float* __restrict__ inputs,
    const float* __restrict__ W_o, const float* __restrict__ b_o,
    const float* __restrict__ r0, const float* __restrict__ w0,
    const uint4* __restrict__ wx2, const uint4* __restrict__ whf8,
    const uint4* __restrict__ wpg,
    const float4* __restrict__ blh, const float* __restrict__ bpp,
    char* comm, float* __restrict__ out)
{
    const int bid = blockIdx.x, hf = bid>>7, b = bid&127;
    const int t = threadIdx.x, wv = t>>6, ln = t&63;
    const int g4 = t>>3, q = t&7;

    char* cb = comm + b*COMM_STRIDE;
    volatile float* hOwn = (volatile float*)(cb + hf*512);
    volatile float* hOth = (volatile float*)(cb + (hf^1)*512);
    volatile float* pOwn = (volatile float*)(cb + 1024 + hf*544);
    volatile float* pOth = (volatile float*)(cb + 1024 + (hf^1)*544);
    volatile int*   flg  = (volatile int*)(cb + 2112);   // [f1A,f1B,f2A,f2B]

    __shared__ uint4 wxL[5120];          // 80KB pinned W_x half (fp16, conflict-free)
    __shared__ uint4 whL8[2][1024];      // 32KB pinned fp8 W_h slices j=0,1 (covers kk p=0..3)
    __shared__ float Mem[NN][MM+1];
    __shared__ float4 gpart4[128];
    __shared__ float4 blhL[128];
    __shared__ float hbuf[U_];
    __shared__ float cbuf[128];
    __shared__ h2_t  hb2[128] __attribute__((aligned(16)));
    __shared__ h2_t  xr2[40] __attribute__((aligned(16)));
    __shared__ float prmS[12];
    __shared__ float scal[12];
    __shared__ float kv[2][MM], ebuf[MM], abuf[MM];
    __shared__ float innr[2][NN], Mn[NN], wgs[2][NN], wtab[2][NN];
    __shared__ float rpart[16][MM];
    __shared__ float jpart[OUT_];

    // ---- init ----
    for (int i=t; i<5120; i+=1024) wxL[i] = wx2[hf*5120 + i];
    for (int i=t; i<2048; i+=1024){
        int j = i>>10, jj = i&1023;
        whL8[j][jj] = whf8[hf*8192 + (jj>>3)*64 + j*8 + (jj&7)];
    }
    for (int i=t; i<NN*MM; i+=1024) Mem[i>>6][i&63] = 1e-6f;
    if (t < 128){
        gpart4[t] = make_float4(0.f,0.f,0.f,0.f);
        blhL[t] = blh[hf*128+t];
        cbuf[t] = 0.f;
        Mn[t] = 8e-6f;
        h2_t z; z.x=(_Float16)0.f; z.y=(_Float16)0.f; hb2[t] = z;
    }
    if (t < U_) hbuf[t] = 0.f;
    if (t >= 128 && t < 256){  // wtab = softmax(w0)
        int h = (t-128)>>6, l = t&63;
        float v0 = w0[h*NN + l], v1 = w0[h*NN + l + 64];
        float mx = fmaxf(v0,v1);
        for (int off=32; off>=1; off>>=1) mx = fmaxf(mx, __shfl_xor(mx, off));
        float e0 = __expf(v0-mx), e1 = __expf(v1-mx);
        float s = e0+e1;
        for (int off=32; off>=1; off>>=1) s += __shfl_xor(s, off);
        wtab[h][l] = e0/s; wtab[h][l+64] = e1/s;
    }
    if (t >= 256 && t < 296){
        int p = t-256;
        h2_t v;
        if (p < 32){ v.x = (_Float16)tanhf(r0[2*p]); v.y = (_Float16)tanhf(r0[2*p+1]); }
        else if (p < 37){
            int e0 = 2*(p-32), e1 = e0+1;
            float f0 = (e0<IN_DIM_) ? inputs[b*T_*IN_DIM_ + e0] : 0.f;
            float f1 = (e1<IN_DIM_) ? inputs[b*T_*IN_DIM_ + e1] : 0.f;
            v.x = (_Float16)f0; v.y = (_Float16)f1;
        } else { v.x=(_Float16)0.f; v.y=(_Float16)0.f; }
        xr2[p] = v;
    }
    __syncthreads();

    for (int step=0; step<T_; ++step){
        // ---- B: gates from pinned wx + gpart + bias, fused LSTM ----
        {
            const uint4* wb = wxL + wv*320;
            float a0=0.f,a1=0.f,a2=0.f,a3=0.f;
            #pragma unroll
            for (int p=0; p<5; ++p){
                uint4 u = wb[p*64 + ln];
                h2_t xv = xr2[q*5+p];
                DOT2X4(u, xv);
            }
            #pragma unroll
            for (int m=1; m<8; m<<=1){
                a0 += __shfl_xor(a0,m); a1 += __shfl_xor(a1,m);
                a2 += __shfl_xor(a2,m); a3 += __shfl_xor(a3,m);
            }
            if (q==0){
                float4 bb = blhL[g4]; float4 gp = gpart4[g4];
                float gi=a0+bb.x+gp.x, gf=a1+bb.y+gp.y, gg=a2+bb.z+gp.z, go=a3+bb.w+gp.w;
                float c = sigf(gf)*cbuf[g4] + sigf(gi)*tanhf(gg);
                cbuf[g4] = c;
                float h = sigf(go)*tanhf(c);
                hbuf[hf*128+g4] = h;
                hOwn[g4] = h;
            }
        }
        __syncthreads();                          // drains volatile h stores
        if (t==0){
            flg[hf] = step+1;
            while (flg[hf^1] < step+1) __builtin_amdgcn_s_sleep(8);
        }
        __syncthreads();
        // pull partner h; build fp16 h pairs
        if (t < 128){
            float hv = hOth[t];
            hbuf[(hf^1)*128 + t] = hv;
            float hv2 = __shfl_down(hv, 1);
            if (!(t&1)){ h2_t vv; vv.x=(_Float16)hv; vv.y=(_Float16)hv2; hb2[(hf^1)*64 + (t>>1)] = vv; }
        } else if (t < 192){
            int jj = t-128;
            h2_t vv; vv.x=(_Float16)hbuf[hf*128+2*jj]; vv.y=(_Float16)hbuf[hf*128+2*jj+1];
            hb2[hf*64+jj] = vv;
        }
        __syncthreads();

        const uint4* hb2q = (const uint4*)hb2;

        // ---- FUSED: gpart (fp8 wh: 2 LDS + 6 streamed uint4) ; wp ; Mn ; jpart ; x-pre ----
        {
            const uint4* wrow = whf8 + hf*8192 + g4*64;
            uint4 hA = hb2q[q*4+0], hB = hb2q[q*4+1], hC = hb2q[q*4+2], hD = hb2q[q*4+3];
            float a0=0.f,a1=0.f,a2=0.f,a3=0.f;
            // issue all 6 streamed loads first
            uint4 s2 = wrow[16+q], s3 = wrow[24+q], s4 = wrow[32+q];
            uint4 s5 = wrow[40+q], s6 = wrow[48+q], s7 = wrow[56+q];
            // LDS slices decode while globals in flight
            uint4 l0 = whL8[0][t], l1 = whL8[1][t];
            DEC8(l0, H2C(hA.x), H2C(hA.y));
            DEC8(l1, H2C(hA.z), H2C(hA.w));
            DEC8(s2, H2C(hB.x), H2C(hB.y));
            DEC8(s3, H2C(hB.z), H2C(hB.w));
            DEC8(s4, H2C(hC.x), H2C(hC.y));
            DEC8(s5, H2C(hC.z), H2C(hC.w));
            DEC8(s6, H2C(hD.x), H2C(hD.y));
            DEC8(s7, H2C(hD.z), H2C(hD.w));
            #pragma unroll
            for (int m=1; m<8; m<<=1){
                a0 += __shfl_xor(a0,m); a1 += __shfl_xor(a1,m);
                a2 += __shfl_xor(a2,m); a3 += __shfl_xor(a3,m);
            }
            if (q==0) gpart4[g4] = make_float4(a0*16.f, a1*16.f, a2*16.f, a3*16.f);
        }
        if (t < 272){
            const int cg = t>>3, qq = t&7;
            const uint4* wrow = wpg + (hf*34+cg)*128;
            uint4 hA = hb2q[qq*4+0], hB = hb2q[qq*4+1], hC = hb2q[qq*4+2], hD = hb2q[qq*4+3];
            float pa0=0.f, pa1=0.f, pa2=0.f, pa3=0.f;
            {
                uint4 u0=wrow[0*8+qq], u1=wrow[1*8+qq], u2=wrow[2*8+qq], u3=wrow[3*8+qq];
                uint4 u4=wrow[4*8+qq], u5=wrow[5*8+qq], u6=wrow[6*8+qq], u7=wrow[7*8+qq];
                DOT2P(u0, H2C(hA.x)); DOT2P(u1, H2C(hA.y));
                DOT2P(u2, H2C(hA.z)); DOT2P(u3, H2C(hA.w));
                DOT2P(u4, H2C(hB.x)); DOT2P(u5, H2C(hB.y));
                DOT2P(u6, H2C(hB.z)); DOT2P(u7, H2C(hB.w));
            }
            {
                uint4 u0=wrow[8*8+qq],  u1=wrow[9*8+qq],  u2=wrow[10*8+qq], u3=wrow[11*8+qq];
                uint4 u4=wrow[12*8+qq], u5=wrow[13*8+qq], u6=wrow[14*8+qq], u7=wrow[15*8+qq];
                DOT2P(u0, H2C(hC.x)); DOT2P(u1, H2C(hC.y));
                DOT2P(u2, H2C(hC.z)); DOT2P(u3, H2C(hC.w));
                DOT2P(u4, H2C(hD.x)); DOT2P(u5, H2C(hD.y));
                DOT2P(u6, H2C(hD.z)); DOT2P(u7, H2C(hD.w));
            }
            #pragma unroll
            for (int m=1; m<8; m<<=1){
                pa0 += __shfl_xor(pa0,m); pa1 += __shfl_xor(pa1,m);
                pa2 += __shfl_xor(pa2,m); pa3 += __shfl_xor(pa3,m);
            }
            if (qq==0){
                #pragma unroll
                for (int j=0; j<4; ++j){
                    float aj = (j==0)?pa0:((j==1)?pa1:((j==2)?pa2:pa3));
                    int cl = cg*4+j;
                    if (cl < 134){
                        int rc = hf*134+cl;
                        float pv = clipf(aj + bpp[rc]);
                        float dv = decodeP(rc, pv);
                        pOwn[cl] = dv;
                        if (rc < 64) kv[0][rc] = dv;
                        else if (rc < 70) prmS[rc-64] = dv;
                        else if (rc < 134) kv[1][rc-70] = dv;
                        else if (rc < 140) prmS[6+rc-134] = dv;
                        else if (rc < 204) ebuf[rc-140] = dv;
                        else abuf[rc-204] = dv;
                    }
                }
            }
        } else if (t < 528){
            const int idx = t-272, n = idx>>1, m0 = (idx&1)*32;
            float s = 0.f;
            #pragma unroll 8
            for (int m=m0; m<m0+32; ++m){ float v=Mem[n][m]; s=fmaf(v,v,s); }
            s += __shfl_xor(s,1);
            if (!(idx&1)) Mn[n] = sqrtf(s);
        } else if (t < 656){
            const int o = (t-528)>>4, l16 = (t-528)&15;
            float s = 0.f;
            #pragma unroll
            for (int j=0; j<16; ++j){
                const int i = l16 + (j<<4);
                s = fmaf(hbuf[i], W_o[i*OUT_ + o], s);
            }
            s += __shfl_xor(s,1); s += __shfl_xor(s,2);
            s += __shfl_xor(s,4); s += __shfl_xor(s,8);
            if (l16==0) jpart[o] = s;
        } else if (t >= 656 && t < 661){
            if (step+1 < T_){
                const int p = t-656;
                const int e0 = 2*p, e1 = e0+1;
                const float* xin = inputs + (b*T_ + step+1)*IN_DIM_;
                h2_t v;
                v.x = (_Float16)((e0<IN_DIM_) ? xin[e0] : 0.f);
                v.y = (_Float16)((e1<IN_DIM_) ? xin[e1] : 0.f);
                xr2[32+p] = v;
            }
        }
        __syncthreads();                          // drains volatile p stores
        if (t==0){
            flg[2+hf] = step+1;
            while (flg[2+(hf^1)] < step+1) __builtin_amdgcn_s_sleep(8);
        }
        __syncthreads();
        if (t < 134){                              // route partner's decoded params
            float dv = pOth[t];
            int rc = (hf^1)*134 + t;
            if (rc < 64) kv[0][rc] = dv;
            else if (rc < 70) prmS[rc-64] = dv;
            else if (rc < 134) kv[1][rc-70] = dv;
            else if (rc < 140) prmS[6+rc-134] = dv;
            else if (rc < 204) ebuf[rc-140] = dv;
            else abuf[rc-204] = dv;
        }
        __syncthreads();

        // ---- F: inner products + scal decode ----
        {
            const int h = t>>9, n = (t>>2)&127, qm = t&3, m0 = qm*16;
            float s = 0.f;
            #pragma unroll 8
            for (int m=m0; m<m0+16; ++m) s = fmaf(kv[h][m], Mem[n][m], s);
            s += __shfl_xor(s,1); s += __shfl_xor(s,2);
            if (qm==0) innr[h][n] = s;
        }
        if (t < 2){
            const int h = t;
            const float* ps = prmS + 6*h;
            scal[h]   = splus(ps[0]);
            scal[2+h] = sigf(ps[1]);
            float p0=ps[2], p1=ps[3], p2=ps[4];
            float mx = fmaxf(p0, fmaxf(p1, p2));
            float e0=__expf(p0-mx), e1=__expf(p1-mx), e2=__expf(p2-mx);
            float s = e0+e1+e2;
            scal[6+3*h]=e0/s; scal[7+3*h]=e1/s; scal[8+3*h]=e2/s;
            scal[4+h] = 1.f + splus(ps[5]);
        }
        __syncthreads();

        // ---- G: key norm + content softmax + interp + shift + sharpen ----
        if (t < 128){
            const int h = t>>6, l = ln;
            float kvl = kv[h][l];
            float kn2 = kvl*kvl;
            for (int off=32; off>=1; off>>=1) kn2 += __shfl_xor(kn2, off);
            float kn = sqrtf(kn2);
            float beta = scal[h], g = scal[2+h];
            float bk0 = beta * innr[h][l]   /(kn*Mn[l]   +1e-8f);
            float bk1 = beta * innr[h][l+64]/(kn*Mn[l+64]+1e-8f);
            float mx = fmaxf(bk0,bk1);
            for (int off=32; off>=1; off>>=1) mx = fmaxf(mx, __shfl_xor(mx, off));
            float e0=__expf(bk0-mx), e1=__expf(bk1-mx);
            float s=e0+e1;
            for (int off=32; off>=1; off>>=1) s += __shfl_xor(s, off);
            float wc0=e0/s, wc1=e1/s;
            wgs[h][l]    = g*wc0 + (1.f-g)*wtab[h][l];
            wgs[h][l+64] = g*wc1 + (1.f-g)*wtab[h][l+64];
            float gamma = scal[4+h];
            float s0=scal[6+3*h], s1=scal[7+3*h], s2=scal[8+3*h];
            const int n0=l, n1=l+64;
            float wt0 = s0*wgs[h][(n0+1)&127] + s1*wgs[h][n0] + s2*wgs[h][(n0+127)&127];
            float wt1 = s0*wgs[h][(n1+1)&127] + s1*wgs[h][n1] + s2*wgs[h][(n1+127)&127];
            float wp0 = __powf(wt0, gamma), wp1 = __powf(wt1, gamma);
            float ss = wp0+wp1;
            for (int off=32; off>=1; off>>=1) ss += __shfl_xor(ss, off);
            float inv = 1.0f/(ss+1e-8f);
            wtab[h][n0] = wp0*inv; wtab[h][n1] = wp1*inv;
        }
        __syncthreads();

        // ---- H: memory write + fused read-head partials ----
        {
            const float el = ebuf[ln], al = abuf[ln];
            const int n0 = wv*8;
            float racc = 0.f;
            #pragma unroll
            for (int k=0; k<8; ++k){
                const int n = n0+k;
                float ww = wtab[1][n];
                float wr = wtab[0][n];
                float v = Mem[n][ln]*(1.0f - ww*el) + ww*al;
                Mem[n][ln] = v;
                racc = fmaf(wr, v, racc);
            }
            rpart[wv][ln] = racc;
        }
        __syncthreads();

        // ---- J: r finalize + output (hf==0 writes) + xr2 r-pack ----
        if (t < 512){
            const int o = wv;
            float rm = 0.f;
            #pragma unroll
            for (int k=0; k<16; ++k) rm += rpart[k][ln];
            float s = rm * W_o[(U_+ln)*OUT_ + o];
            for (int off=32; off>=1; off>>=1) s += __shfl_xor(s, off);
            if (ln==0 && hf==0 && step>=TSTART){
                float logit = clipf(s + jpart[o] + b_o[o]);
                out[((b*(T_-TSTART)) + (step-TSTART))*OUT_ + o] = sigf(logit);
            }
        } else if (t < 576){
            float rm = 0.f;
            #pragma unroll
            for (int k=0; k<16; ++k) rm += rpart[k][ln];
            float other = __shfl_xor(rm, 1);
            if (!(ln&1)){
                h2_t v; v.x = (_Float16)rm; v.y = (_Float16)other;
                xr2[ln>>1] = v;
            }
        }
        __syncthreads();
    }
}

extern "C" void kernel_launch(void* const* d_in, const int* in_sizes, int n_in,
                              void* d_out, int out_size, void* d_ws, size_t ws_size,
                              hipStream_t stream) {
    const float* inputs = (const float*)d_in[0];
    const float* W_x    = (const float*)d_in[1];
    const float* W_h    = (const float*)d_in[2];
    const float* b_lstm = (const float*)d_in[3];
    const float* W_p    = (const float*)d_in[4];
    const float* b_p    = (const float*)d_in[5];
    const float* W_o    = (const float*)d_in[6];
    const float* b_o    = (const float*)d_in[7];
    const float* r0     = (const float*)d_in[8];
    const float* w0     = (const float*)d_in[9];
    float* out = (float*)d_out;

    char* ws = (char*)d_ws;
    uint4*  wx2 = (uint4*)(ws + WX2_OFF);
    uint4*  wh8 = (uint4*)(ws + WH8_OFF);
    uint4*  wp2 = (uint4*)(ws + WPG_OFF);
    float4* blh = (float4*)(ws + BLH_OFF);
    float*  bpp = (float*)(ws + BPP_OFF);
    char*   comm = ws + COMM_OFF;

    hipMemsetAsync(comm, 0, COMM_SZ, stream);
    prep_kernel<<<512, 256, 0, stream>>>(W_x, W_h, W_p, b_lstm, b_p, wx2, wh8, wp2, blh, bpp);
    ntm_kernel<<<2*B_, 1024, 0, stream>>>(inputs, W_o, b_o, r0, w0,
                                          wx2, wh8, wp2, blh, bpp, comm, out);
}

// Round 17
// 1799.956 us; speedup vs baseline: 1.6743x; 1.1611x over previous
//
#include <hip/hip_runtime.h>
#include <math.h>

typedef _Float16 h2_t __attribute__((ext_vector_type(2)));

#define U_ 256
#define NN 128
#define MM 64
#define OUT_ 8
#define CLIPV 20.0f
#define IN_DIM_ 9
#define PP 268
#define B_ 128
#define T_ 130
#define TSTART 65

// ws element counts / byte offsets
#define NWX2 10240      // 2hf * 16wv * 5p * 64ln      (uint4 fp16, conflict-free pinned)
#define NWH8 16384      // 2hf * 128g4 * 64slot(j*8+q) (uint4 = 16 fp8: 4col x 4k)
#define NWP8 4352       // 68cg * 64slot(j*8+q)        (uint4 fp8, FULL width, kb=q*32+4j)
#define WX2_OFF 0
#define WH8_OFF 163840
#define WP8_OFF 425984
#define BLH_OFF 495616
#define BPP_OFF 499712
#define COMM_OFF 500800
#define COMM_STRIDE 2176          // hA512|hB512|(unused)|flags|pad
#define COMM_SZ (B_*COMM_STRIDE)
#define PREP_N (NWX2 + NWH8 + NWP8 + 256 + 272)

__device__ __forceinline__ float sigf(float x){ return 1.0f/(1.0f+__expf(-x)); }
__device__ __forceinline__ float splus(float x){ return log1pf(__expf(x)); }
__device__ __forceinline__ float clipf(float x){ return fminf(fmaxf(x,-CLIPV),CLIPV); }

#if defined(__has_builtin)
#if __has_builtin(__builtin_amdgcn_fdot2)
#define DOT2(a,b,c) __builtin_amdgcn_fdot2((a),(b),(c),false)
#endif
#endif
#ifndef DOT2
#define DOT2(a,b,c) fmaf((float)(a).x,(float)(b).x, fmaf((float)(a).y,(float)(b).y,(c)))
#endif

#define DOT2X4(uu, hv) { \
    a0 = DOT2(hv, __builtin_bit_cast(h2_t,(uu).x), a0); \
    a1 = DOT2(hv, __builtin_bit_cast(h2_t,(uu).y), a1); \
    a2 = DOT2(hv, __builtin_bit_cast(h2_t,(uu).z), a2); \
    a3 = DOT2(hv, __builtin_bit_cast(h2_t,(uu).w), a3); }
#define H2C(hu) __builtin_bit_cast(h2_t,(hu))

// fp8 e4m3 decode: word = bytes [k0,k2,k1,k3]; outA = h2(k0,k1), outB = h2(k2,k3),
// each fp16 value = stored_value/256 (x16 net scale folded into final use).
#define DEC1(vv, aa, hX, hY) { \
    unsigned oA = (((vv)<<7)&0x3F803F80u)|(((vv)<<8)&0x80008000u); \
    unsigned oB = (((vv)>>1)&0x3F803F80u)|((vv)&0x80008000u); \
    aa = DOT2(hX, H2C(oA), aa); aa = DOT2(hY, H2C(oB), aa); }
#define DEC8(u, hX, hY) { \
    DEC1((u).x, a0, hX, hY); DEC1((u).y, a1, hX, hY); \
    DEC1((u).z, a2, hX, hY); DEC1((u).w, a3, hX, hY); }
#define DEC8P(u, hX, hY) { \
    DEC1((u).x, pa0, hX, hY); DEC1((u).y, pa1, hX, hY); \
    DEC1((u).z, pa2, hX, hY); DEC1((u).w, pa3, hX, hY); }

__device__ __forceinline__ unsigned packh2(float a, float b){
    h2_t v; v.x = (_Float16)a; v.y = (_Float16)b;
    return __builtin_bit_cast(unsigned, v);
}

// encode w -> e4m3 byte of (w*16): via fp16(w/16) bits >> 7, RTNE
__device__ __forceinline__ unsigned enc8(float w){
    _Float16 h = (_Float16)(w * 0.0625f);
    unsigned short hb = __builtin_bit_cast(unsigned short, h);
    unsigned s = ((unsigned)hb >> 8) & 0x80u;
    unsigned mag = (unsigned)hb & 0x7FFFu;
    unsigned b = (mag + 0x3Fu + ((mag>>7)&1u)) >> 7;
    if (b > 0x7Fu) b = 0x7Fu;
    return s | b;
}

__global__ void prep_kernel(const float* __restrict__ W_x, const float* __restrict__ W_h,
                            const float* __restrict__ W_p, const float* __restrict__ b_lstm,
                            const float* __restrict__ b_p,
                            uint4* __restrict__ wx2, uint4* __restrict__ whf8,
                            uint4* __restrict__ wpf8,
                            float4* __restrict__ blh, float* __restrict__ bpp)
{
    for (int idx = blockIdx.x*blockDim.x + threadIdx.x; idx < PREP_N; idx += gridDim.x*blockDim.x){
        if (idx < NWX2){
            // conflict-free pinned layout: [hf][wv][p][ln]
            int hf = idx/5120, rem = idx - hf*5120;
            int wv = rem/320, r2 = rem - wv*320, p = r2>>6, ln = r2&63;
            int g4 = wv*8 + (ln>>3), q = ln&7, kk = q*5+p;
            int k0 = 2*kk, k1 = k0+1;
            unsigned c[4];
            #pragma unroll
            for (int g=0; g<4; ++g){
                int col = g*256 + hf*128 + g4;
                float f0 = (k0<64) ? W_x[(9+k0)*1024+col] : (k0<73 ? W_x[(k0-64)*1024+col] : 0.f);
                float f1 = (k1<64) ? W_x[(9+k1)*1024+col] : (k1<73 ? W_x[(k1-64)*1024+col] : 0.f);
                c[g] = packh2(f0,f1);
            }
            wx2[idx] = make_uint4(c[0],c[1],c[2],c[3]);
        } else if (idx < NWX2 + NWH8){
            // fp8 W_h: [hf][g4][slot j*8+q]; word g = col(g)'s k-values [k0,k2,k1,k3], kbase=q*32+4j
            int e = idx - NWX2;
            int hf = e>>13, rem = e&8191, g4 = rem>>6, s = rem&63;
            int j = s>>3, q = s&7, kb = q*32 + 4*j;
            unsigned c[4];
            #pragma unroll
            for (int g=0; g<4; ++g){
                int col = g*256 + hf*128 + g4;
                unsigned b0 = enc8(W_h[(kb+0)*1024+col]);
                unsigned b1 = enc8(W_h[(kb+2)*1024+col]);
                unsigned b2 = enc8(W_h[(kb+1)*1024+col]);
                unsigned b3 = enc8(W_h[(kb+3)*1024+col]);
                c[g] = b0 | (b1<<8) | (b2<<16) | (b3<<24);
            }
            whf8[e] = make_uint4(c[0],c[1],c[2],c[3]);
        } else if (idx < NWX2 + NWH8 + NWP8){
            // fp8 W_p FULL width: [cg][slot j*8+q]; word g = col(cg*4+g), k base q*32+4j
            int e = idx - NWX2 - NWH8;
            int cg = e>>6, s = e&63;
            int j = s>>3, q = s&7, kb = q*32 + 4*j;
            unsigned c[4];
            #pragma unroll
            for (int g=0; g<4; ++g){
                int cl = cg*4+g;
                if (cl < PP){
                    unsigned b0 = enc8(W_p[(kb+0)*PP+cl]);
                    unsigned b1 = enc8(W_p[(kb+2)*PP+cl]);
                    unsigned b2 = enc8(W_p[(kb+1)*PP+cl]);
                    unsigned b3 = enc8(W_p[(kb+3)*PP+cl]);
                    c[g] = b0 | (b1<<8) | (b2<<16) | (b3<<24);
                } else c[g] = 0u;
            }
            wpf8[e] = make_uint4(c[0],c[1],c[2],c[3]);
        } else if (idx < NWX2 + NWH8 + NWP8 + 256){
            int u = idx - NWX2 - NWH8 - NWP8;
            blh[u] = make_float4(b_lstm[u], b_lstm[256+u], b_lstm[512+u], b_lstm[768+u]);
        } else {
            int j = idx - NWX2 - NWH8 - NWP8 - 256;
            bpp[j] = (j < PP) ? b_p[j] : 0.f;
        }
    }
}

__device__ __forceinline__ float decodeP(int rc, float p){
    if (rc < 64 || (rc >= 70 && rc < 134) || rc >= 204) return tanhf(p);
    if (rc >= 140 && rc < 204) return sigf(p);
    return p;
}

__global__ __launch_bounds__(1024,1) void ntm_kernel(
    const float* __restrict__ inputs,
    const float* __restrict__ W_o, const float* __restrict__ b_o,
    const float* __restrict__ r0, const float* __restrict__ w0,
    const uint4* __restrict__ wx2, const uint4* __restrict__ whf8,
    const uint4* __restrict__ wpf8,
    const float4* __restrict__ blh, const float* __restrict__ bpp,
    char* comm, float* __restrict__ out)
{
    const int bid = blockIdx.x, hf = bid>>7, b = bid&127;
    const int t = threadIdx.x, wv = t>>6, ln = t&63;
    const int g4 = t>>3, q = t&7;

    char* cb = comm + b*COMM_STRIDE;
    volatile float* hOwn = (volatile float*)(cb + hf*512);
    volatile float* hOth = (volatile float*)(cb + (hf^1)*512);
    volatile int*   flg  = (volatile int*)(cb + 2112);   // [f1A,f1B]

    __shared__ uint4 wxL[5120];          // 80KB pinned W_x half (fp16, conflict-free)
    __shared__ uint4 whL8[2][1024];      // 32KB pinned fp8 W_h slices j=0,1
    __shared__ float Mem[NN][MM+1];
    __shared__ float4 gpart4[128];
    __shared__ float4 blhL[128];
    __shared__ float hbuf[U_];
    __shared__ float cbuf[128];
    __shared__ h2_t  hb2[128] __attribute__((aligned(16)));
    __shared__ h2_t  xr2[40] __attribute__((aligned(16)));
    __shared__ float prmS[12];
    __shared__ float scal[12];
    __shared__ float kv[2][MM], ebuf[MM], abuf[MM];
    __shared__ float innr[2][NN], Mn[NN], wgs[2][NN], wtab[2][NN];
    __shared__ float rpart[16][MM];
    __shared__ float jpart[OUT_];

    // ---- init ----
    for (int i=t; i<5120; i+=1024) wxL[i] = wx2[hf*5120 + i];
    for (int i=t; i<2048; i+=1024){
        int j = i>>10, jj = i&1023;
        whL8[j][jj] = whf8[hf*8192 + (jj>>3)*64 + j*8 + (jj&7)];
    }
    for (int i=t; i<NN*MM; i+=1024) Mem[i>>6][i&63] = 1e-6f;
    if (t < 128){
        gpart4[t] = make_float4(0.f,0.f,0.f,0.f);
        blhL[t] = blh[hf*128+t];
        cbuf[t] = 0.f;
        Mn[t] = 8e-6f;
        h2_t z; z.x=(_Float16)0.f; z.y=(_Float16)0.f; hb2[t] = z;
    }
    if (t < U_) hbuf[t] = 0.f;
    if (t >= 128 && t < 256){  // wtab = softmax(w0)
        int h = (t-128)>>6, l = t&63;
        float v0 = w0[h*NN + l], v1 = w0[h*NN + l + 64];
        float mx = fmaxf(v0,v1);
        for (int off=32; off>=1; off>>=1) mx = fmaxf(mx, __shfl_xor(mx, off));
        float e0 = __expf(v0-mx), e1 = __expf(v1-mx);
        float s = e0+e1;
        for (int off=32; off>=1; off>>=1) s += __shfl_xor(s, off);
        wtab[h][l] = e0/s; wtab[h][l+64] = e1/s;
    }
    if (t >= 256 && t < 296){
        int p = t-256;
        h2_t v;
        if (p < 32){ v.x = (_Float16)tanhf(r0[2*p]); v.y = (_Float16)tanhf(r0[2*p+1]); }
        else if (p < 37){
            int e0 = 2*(p-32), e1 = e0+1;
            float f0 = (e0<IN_DIM_) ? inputs[b*T_*IN_DIM_ + e0] : 0.f;
            float f1 = (e1<IN_DIM_) ? inputs[b*T_*IN_DIM_ + e1] : 0.f;
            v.x = (_Float16)f0; v.y = (_Float16)f1;
        } else { v.x=(_Float16)0.f; v.y=(_Float16)0.f; }
        xr2[p] = v;
    }
    __syncthreads();

    for (int step=0; step<T_; ++step){
        // ---- B: gates from pinned wx + gpart + bias, fused LSTM ----
        {
            const uint4* wb = wxL + wv*320;
            float a0=0.f,a1=0.f,a2=0.f,a3=0.f;
            #pragma unroll
            for (int p=0; p<5; ++p){
                uint4 u = wb[p*64 + ln];
                h2_t xv = xr2[q*5+p];
                DOT2X4(u, xv);
            }
            #pragma unroll
            for (int m=1; m<8; m<<=1){
                a0 += __shfl_xor(a0,m); a1 += __shfl_xor(a1,m);
                a2 += __shfl_xor(a2,m); a3 += __shfl_xor(a3,m);
            }
            if (q==0){
                float4 bb = blhL[g4]; float4 gp = gpart4[g4];
                float gi=a0+bb.x+gp.x, gf=a1+bb.y+gp.y, gg=a2+bb.z+gp.z, go=a3+bb.w+gp.w;
                float c = sigf(gf)*cbuf[g4] + sigf(gi)*tanhf(gg);
                cbuf[g4] = c;
                float h = sigf(go)*tanhf(c);
                hbuf[hf*128+g4] = h;
                hOwn[g4] = h;
            }
        }
        __syncthreads();                          // drains volatile h stores
        if (t==0){
            flg[hf] = step+1;
            while (flg[hf^1] < step+1) __builtin_amdgcn_s_sleep(8);
        }
        __syncthreads();
        // pull partner h; build fp16 h pairs
        if (t < 128){
            float hv = hOth[t];
            hbuf[(hf^1)*128 + t] = hv;
            float hv2 = __shfl_down(hv, 1);
            if (!(t&1)){ h2_t vv; vv.x=(_Float16)hv; vv.y=(_Float16)hv2; hb2[(hf^1)*64 + (t>>1)] = vv; }
        } else if (t < 192){
            int jj = t-128;
            h2_t vv; vv.x=(_Float16)hbuf[hf*128+2*jj]; vv.y=(_Float16)hbuf[hf*128+2*jj+1];
            hb2[hf*64+jj] = vv;
        }
        __syncthreads();

        const uint4* hb2q = (const uint4*)hb2;

        // ---- FUSED: gpart (fp8 wh) ; params fp8 FULL (t<544) ; Mn ; jpart ; x-pre ----
        {
            const uint4* wrow = whf8 + hf*8192 + g4*64;
            uint4 hA = hb2q[q*4+0], hB = hb2q[q*4+1], hC = hb2q[q*4+2], hD = hb2q[q*4+3];
            float a0=0.f,a1=0.f,a2=0.f,a3=0.f;
            uint4 s2 = wrow[16+q], s3 = wrow[24+q], s4 = wrow[32+q];
            uint4 s5 = wrow[40+q], s6 = wrow[48+q], s7 = wrow[56+q];
            uint4 l0 = whL8[0][t], l1 = whL8[1][t];
            DEC8(l0, H2C(hA.x), H2C(hA.y));
            DEC8(l1, H2C(hA.z), H2C(hA.w));
            DEC8(s2, H2C(hB.x), H2C(hB.y));
            DEC8(s3, H2C(hB.z), H2C(hB.w));
            DEC8(s4, H2C(hC.x), H2C(hC.y));
            DEC8(s5, H2C(hC.z), H2C(hC.w));
            DEC8(s6, H2C(hD.x), H2C(hD.y));
            DEC8(s7, H2C(hD.z), H2C(hD.w));
            #pragma unroll
            for (int m=1; m<8; m<<=1){
                a0 += __shfl_xor(a0,m); a1 += __shfl_xor(a1,m);
                a2 += __shfl_xor(a2,m); a3 += __shfl_xor(a3,m);
            }
            if (q==0) gpart4[g4] = make_float4(a0*16.f, a1*16.f, a2*16.f, a3*16.f);
        }
        if (t < 544){
            const int cg = t>>3, qq = t&7;
            const uint4* wrow = wpf8 + cg*64;
            uint4 hA = hb2q[qq*4+0], hB = hb2q[qq*4+1], hC = hb2q[qq*4+2], hD = hb2q[qq*4+3];
            float pa0=0.f, pa1=0.f, pa2=0.f, pa3=0.f;
            uint4 u0=wrow[0*8+qq], u1=wrow[1*8+qq], u2=wrow[2*8+qq], u3=wrow[3*8+qq];
            uint4 u4=wrow[4*8+qq], u5=wrow[5*8+qq], u6=wrow[6*8+qq], u7=wrow[7*8+qq];
            DEC8P(u0, H2C(hA.x), H2C(hA.y));
            DEC8P(u1, H2C(hA.z), H2C(hA.w));
            DEC8P(u2, H2C(hB.x), H2C(hB.y));
            DEC8P(u3, H2C(hB.z), H2C(hB.w));
            DEC8P(u4, H2C(hC.x), H2C(hC.y));
            DEC8P(u5, H2C(hC.z), H2C(hC.w));
            DEC8P(u6, H2C(hD.x), H2C(hD.y));
            DEC8P(u7, H2C(hD.z), H2C(hD.w));
            #pragma unroll
            for (int m=1; m<8; m<<=1){
                pa0 += __shfl_xor(pa0,m); pa1 += __shfl_xor(pa1,m);
                pa2 += __shfl_xor(pa2,m); pa3 += __shfl_xor(pa3,m);
            }
            if (qq==0){
                #pragma unroll
                for (int j=0; j<4; ++j){
                    float aj = (j==0)?pa0:((j==1)?pa1:((j==2)?pa2:pa3));
                    int cl = cg*4+j;
                    if (cl < PP){
                        float pv = clipf(aj*16.f + bpp[cl]);
                        float dv = decodeP(cl, pv);
                        if (cl < 64) kv[0][cl] = dv;
                        else if (cl < 70) prmS[cl-64] = dv;
                        else if (cl < 134) kv[1][cl-70] = dv;
                        else if (cl < 140) prmS[6+cl-134] = dv;
                        else if (cl < 204) ebuf[cl-140] = dv;
                        else abuf[cl-204] = dv;
                    }
                }
            }
        } else if (t < 800){
            const int idx = t-544, n = idx>>1, m0 = (idx&1)*32;
            float s = 0.f;
            #pragma unroll 8
            for (int m=m0; m<m0+32; ++m){ float v=Mem[n][m]; s=fmaf(v,v,s); }
            s += __shfl_xor(s,1);
            if (!(idx&1)) Mn[n] = sqrtf(s);
        } else if (t < 928){
            const int o = (t-800)>>4, l16 = (t-800)&15;
            float s = 0.f;
            #pragma unroll
            for (int j=0; j<16; ++j){
                const int i = l16 + (j<<4);
                s = fmaf(hbuf[i], W_o[i*OUT_ + o], s);
            }
            s += __shfl_xor(s,1); s += __shfl_xor(s,2);
            s += __shfl_xor(s,4); s += __shfl_xor(s,8);
            if (l16==0) jpart[o] = s;
        } else if (t < 933){
            if (step+1 < T_){
                const int p = t-928;
                const int e0 = 2*p, e1 = e0+1;
                const float* xin = inputs + (b*T_ + step+1)*IN_DIM_;
                h2_t v;
                v.x = (_Float16)((e0<IN_DIM_) ? xin[e0] : 0.f);
                v.y = (_Float16)((e1<IN_DIM_) ? xin[e1] : 0.f);
                xr2[32+p] = v;
            }
        }
        __syncthreads();

        // ---- F: inner products + scal decode ----
        {
            const int h = t>>9, n = (t>>2)&127, qm = t&3, m0 = qm*16;
            float s = 0.f;
            #pragma unroll 8
            for (int m=m0; m<m0+16; ++m) s = fmaf(kv[h][m], Mem[n][m], s);
            s += __shfl_xor(s,1); s += __shfl_xor(s,2);
            if (qm==0) innr[h][n] = s;
        }
        if (t < 2){
            const int h = t;
            const float* ps = prmS + 6*h;
            scal[h]   = splus(ps[0]);
            scal[2+h] = sigf(ps[1]);
            float p0=ps[2], p1=ps[3], p2=ps[4];
            float mx = fmaxf(p0, fmaxf(p1, p2));
            float e0=__expf(p0-mx), e1=__expf(p1-mx), e2=__expf(p2-mx);
            float s = e0+e1+e2;
            scal[6+3*h]=e0/s; scal[7+3*h]=e1/s; scal[8+3*h]=e2/s;
            scal[4+h] = 1.f + splus(ps[5]);
        }
        __syncthreads();

        // ---- G: key norm + content softmax + interp + shift + sharpen ----
        if (t < 128){
            const int h = t>>6, l = ln;
            float kvl = kv[h][l];
            float kn2 = kvl*kvl;
            for (int off=32; off>=1; off>>=1) kn2 += __shfl_xor(kn2, off);
            float kn = sqrtf(kn2);
            float beta = scal[h], g = scal[2+h];
            float bk0 = beta * innr[h][l]   /(kn*Mn[l]   +1e-8f);
            float bk1 = beta * innr[h][l+64]/(kn*Mn[l+64]+1e-8f);
            float mx = fmaxf(bk0,bk1);
            for (int off=32; off>=1; off>>=1) mx = fmaxf(mx, __shfl_xor(mx, off));
            float e0=__expf(bk0-mx), e1=__expf(bk1-mx);
            float s=e0+e1;
            for (int off=32; off>=1; off>>=1) s += __shfl_xor(s, off);
            float wc0=e0/s, wc1=e1/s;
            wgs[h][l]    = g*wc0 + (1.f-g)*wtab[h][l];
            wgs[h][l+64] = g*wc1 + (1.f-g)*wtab[h][l+64];
            float gamma = scal[4+h];
            float s0=scal[6+3*h], s1=scal[7+3*h], s2=scal[8+3*h];
            const int n0=l, n1=l+64;
            float wt0 = s0*wgs[h][(n0+1)&127] + s1*wgs[h][n0] + s2*wgs[h][(n0+127)&127];
            float wt1 = s0*wgs[h][(n1+1)&127] + s1*wgs[h][n1] + s2*wgs[h][(n1+127)&127];
            float wp0 = __powf(wt0, gamma), wp1 = __powf(wt1, gamma);
            float ss = wp0+wp1;
            for (int off=32; off>=1; off>>=1) ss += __shfl_xor(ss, off);
            float inv = 1.0f/(ss+1e-8f);
            wtab[h][n0] = wp0*inv; wtab[h][n1] = wp1*inv;
        }
        __syncthreads();

        // ---- H: memory write + fused read-head partials ----
        {
            const float el = ebuf[ln], al = abuf[ln];
            const int n0 = wv*8;
            float racc = 0.f;
            #pragma unroll
            for (int k=0; k<8; ++k){
                const int n = n0+k;
                float ww = wtab[1][n];
                float wr = wtab[0][n];
                float v = Mem[n][ln]*(1.0f - ww*el) + ww*al;
                Mem[n][ln] = v;
                racc = fmaf(wr, v, racc);
            }
            rpart[wv][ln] = racc;
        }
        __syncthreads();

        // ---- J: r finalize + output (hf==0 writes) + xr2 r-pack ----
        if (t < 512){
            const int o = wv;
            float rm = 0.f;
            #pragma unroll
            for (int k=0; k<16; ++k) rm += rpart[k][ln];
            float s = rm * W_o[(U_+ln)*OUT_ + o];
            for (int off=32; off>=1; off>>=1) s += __shfl_xor(s, off);
            if (ln==0 && hf==0 && step>=TSTART){
                float logit = clipf(s + jpart[o] + b_o[o]);
                out[((b*(T_-TSTART)) + (step-TSTART))*OUT_ + o] = sigf(logit);
            }
        } else if (t < 576){
            float rm = 0.f;
            #pragma unroll
            for (int k=0; k<16; ++k) rm += rpart[k][ln];
            float other = __shfl_xor(rm, 1);
            if (!(ln&1)){
                h2_t v; v.x = (_Float16)rm; v.y = (_Float16)other;
                xr2[ln>>1] = v;
            }
        }
        __syncthreads();
    }
}

extern "C" void kernel_launch(void* const* d_in, const int* in_sizes, int n_in,
                              void* d_out, int out_size, void* d_ws, size_t ws_size,
                              hipStream_t stream) {
    const float* inputs = (const float*)d_in[0];
    const float* W_x    = (const float*)d_in[1];
    const float* W_h    = (const float*)d_in[2];
    const float* b_lstm = (const float*)d_in[3];
    const float* W_p    = (const float*)d_in[4];
    const float* b_p    = (const float*)d_in[5];
    const float* W_o    = (const float*)d_in[6];
    const float* b_o    = (const float*)d_in[7];
    const float* r0     = (const float*)d_in[8];
    const float* w0     = (const float*)d_in[9];
    float* out = (float*)d_out;

    char* ws = (char*)d_ws;
    uint4*  wx2 = (uint4*)(ws + WX2_OFF);
    uint4*  wh8 = (uint4*)(ws + WH8_OFF);
    uint4*  wp8 = (uint4*)(ws + WP8_OFF);
    float4* blh = (float4*)(ws + BLH_OFF);
    float*  bpp = (float*)(ws + BPP_OFF);
    char*   comm = ws + COMM_OFF;

    hipMemsetAsync(comm, 0, COMM_SZ, stream);
    prep_kernel<<<512, 256, 0, stream>>>(W_x, W_h, W_p, b_lstm, b_p, wx2, wh8, wp8, blh, bpp);
    ntm_kernel<<<2*B_, 1024, 0, stream>>>(inputs, W_o, b_o, r0, w0,
                                          wx2, wh8, wp8, blh, bpp, comm, out);
}

// Round 18
// 1612.964 us; speedup vs baseline: 1.8684x; 1.1159x over previous
//
#include <hip/hip_runtime.h>
#include <math.h>

typedef _Float16 h2_t __attribute__((ext_vector_type(2)));

#define U_ 256
#define NN 128
#define MM 64
#define OUT_ 8
#define CLIPV 20.0f
#define IN_DIM_ 9
#define PP 268
#define B_ 128
#define T_ 130
#define TSTART 65

// ws element counts / byte offsets
#define NWX2 10240      // 2hf * 16wv * 5p * 64ln      (uint4 fp16, conflict-free pinned)
#define NWH8 16384      // 2hf * 128g4 * 64slot(j*8+q) (uint4 = 16 int8: 4col x 4k, kb=q*32+4j)
#define NWP8 4352       // 68cg * 64slot(j*8+q)        (uint4 int8, FULL width, kb=q*32+4j)
#define WX2_OFF 0
#define WH8_OFF 163840
#define WP8_OFF 425984
#define BLH_OFF 495616
#define BPP_OFF 499712
#define COMM_OFF 500800
#define COMM_STRIDE 2176          // hA512|hB512|(unused)|flags|pad
#define COMM_SZ (B_*COMM_STRIDE)
#define PREP_N (NWX2 + NWH8 + NWP8 + 256 + 272)

#define WSCALE 256.f
#define HSCALE 127.f
#define OSCALE (1.f/(256.f*127.f))

__device__ __forceinline__ float sigf(float x){ return 1.0f/(1.0f+__expf(-x)); }
__device__ __forceinline__ float splus(float x){ return log1pf(__expf(x)); }
__device__ __forceinline__ float clipf(float x){ return fminf(fmaxf(x,-CLIPV),CLIPV); }

#if defined(__has_builtin)
#if __has_builtin(__builtin_amdgcn_fdot2)
#define DOT2(a,b,c) __builtin_amdgcn_fdot2((a),(b),(c),false)
#endif
#endif
#ifndef DOT2
#define DOT2(a,b,c) fmaf((float)(a).x,(float)(b).x, fmaf((float)(a).y,(float)(b).y,(c)))
#endif

#if defined(__has_builtin)
#if __has_builtin(__builtin_amdgcn_sdot4)
#define SDOT4(a,b,c) __builtin_amdgcn_sdot4((a),(b),(c),false)
#endif
#endif
#ifndef SDOT4
__device__ __forceinline__ int sdot4_sw(int a, int b, int c){
    c += (int)(signed char)(a      ) * (int)(signed char)(b      );
    c += (int)(signed char)(a >> 8 ) * (int)(signed char)(b >> 8 );
    c += (int)(signed char)(a >> 16) * (int)(signed char)(b >> 16);
    c += (a >> 24) * (b >> 24);
    return c;
}
#define SDOT4(a,b,c) sdot4_sw((a),(b),(c))
#endif

#define DOT2X4(uu, hv) { \
    a0 = DOT2(hv, __builtin_bit_cast(h2_t,(uu).x), a0); \
    a1 = DOT2(hv, __builtin_bit_cast(h2_t,(uu).y), a1); \
    a2 = DOT2(hv, __builtin_bit_cast(h2_t,(uu).z), a2); \
    a3 = DOT2(hv, __builtin_bit_cast(h2_t,(uu).w), a3); }
#define SD4(u, hw) { \
    a0 = SDOT4((int)(u).x, hw, a0); a1 = SDOT4((int)(u).y, hw, a1); \
    a2 = SDOT4((int)(u).z, hw, a2); a3 = SDOT4((int)(u).w, hw, a3); }
#define SD4P(u, hw) { \
    pa0 = SDOT4((int)(u).x, hw, pa0); pa1 = SDOT4((int)(u).y, hw, pa1); \
    pa2 = SDOT4((int)(u).z, hw, pa2); pa3 = SDOT4((int)(u).w, hw, pa3); }
#define H2C(hu) __builtin_bit_cast(h2_t,(hu))

__device__ __forceinline__ unsigned packh2(float a, float b){
    h2_t v; v.x = (_Float16)a; v.y = (_Float16)b;
    return __builtin_bit_cast(unsigned, v);
}

// encode w -> int8 byte of round(w*256), clamped
__device__ __forceinline__ unsigned ei8(float w){
    int v = (int)rintf(w * WSCALE);
    v = v < -127 ? -127 : (v > 127 ? 127 : v);
    return (unsigned)(v & 0xFF);
}

__device__ __forceinline__ unsigned packi8x4(float a, float b, float c, float d){
    int va = (int)rintf(a * HSCALE); va = va < -127 ? -127 : (va > 127 ? 127 : va);
    int vb = (int)rintf(b * HSCALE); vb = vb < -127 ? -127 : (vb > 127 ? 127 : vb);
    int vc = (int)rintf(c * HSCALE); vc = vc < -127 ? -127 : (vc > 127 ? 127 : vc);
    int vd = (int)rintf(d * HSCALE); vd = vd < -127 ? -127 : (vd > 127 ? 127 : vd);
    return (va & 0xFF) | ((vb & 0xFF) << 8) | ((vc & 0xFF) << 16) | ((vd & 0xFF) << 24);
}

__global__ void prep_kernel(const float* __restrict__ W_x, const float* __restrict__ W_h,
                            const float* __restrict__ W_p, const float* __restrict__ b_lstm,
                            const float* __restrict__ b_p,
                            uint4* __restrict__ wx2, uint4* __restrict__ whi8,
                            uint4* __restrict__ wpi8,
                            float4* __restrict__ blh, float* __restrict__ bpp)
{
    for (int idx = blockIdx.x*blockDim.x + threadIdx.x; idx < PREP_N; idx += gridDim.x*blockDim.x){
        if (idx < NWX2){
            // conflict-free pinned layout: [hf][wv][p][ln]
            int hf = idx/5120, rem = idx - hf*5120;
            int wv = rem/320, r2 = rem - wv*320, p = r2>>6, ln = r2&63;
            int g4 = wv*8 + (ln>>3), q = ln&7, kk = q*5+p;
            int k0 = 2*kk, k1 = k0+1;
            unsigned c[4];
            #pragma unroll
            for (int g=0; g<4; ++g){
                int col = g*256 + hf*128 + g4;
                float f0 = (k0<64) ? W_x[(9+k0)*1024+col] : (k0<73 ? W_x[(k0-64)*1024+col] : 0.f);
                float f1 = (k1<64) ? W_x[(9+k1)*1024+col] : (k1<73 ? W_x[(k1-64)*1024+col] : 0.f);
                c[g] = packh2(f0,f1);
            }
            wx2[idx] = make_uint4(c[0],c[1],c[2],c[3]);
        } else if (idx < NWX2 + NWH8){
            // int8 W_h: [hf][g4][slot j*8+q]; word g = col(g)'s k bytes [kb..kb+3], kb=q*32+4j
            int e = idx - NWX2;
            int hf = e>>13, rem = e&8191, g4 = rem>>6, s = rem&63;
            int j = s>>3, q = s&7, kb = q*32 + 4*j;
            unsigned c[4];
            #pragma unroll
            for (int g=0; g<4; ++g){
                int col = g*256 + hf*128 + g4;
                c[g] = ei8(W_h[(kb+0)*1024+col])
                     | (ei8(W_h[(kb+1)*1024+col]) << 8)
                     | (ei8(W_h[(kb+2)*1024+col]) << 16)
                     | (ei8(W_h[(kb+3)*1024+col]) << 24);
            }
            whi8[e] = make_uint4(c[0],c[1],c[2],c[3]);
        } else if (idx < NWX2 + NWH8 + NWP8){
            // int8 W_p FULL width: [cg][slot j*8+q]; word g = col(cg*4+g), kb=q*32+4j
            int e = idx - NWX2 - NWH8;
            int cg = e>>6, s = e&63;
            int j = s>>3, q = s&7, kb = q*32 + 4*j;
            unsigned c[4];
            #pragma unroll
            for (int g=0; g<4; ++g){
                int cl = cg*4+g;
                if (cl < PP){
                    c[g] = ei8(W_p[(kb+0)*PP+cl])
                         | (ei8(W_p[(kb+1)*PP+cl]) << 8)
                         | (ei8(W_p[(kb+2)*PP+cl]) << 16)
                         | (ei8(W_p[(kb+3)*PP+cl]) << 24);
                } else c[g] = 0u;
            }
            wpi8[e] = make_uint4(c[0],c[1],c[2],c[3]);
        } else if (idx < NWX2 + NWH8 + NWP8 + 256){
            int u = idx - NWX2 - NWH8 - NWP8;
            blh[u] = make_float4(b_lstm[u], b_lstm[256+u], b_lstm[512+u], b_lstm[768+u]);
        } else {
            int j = idx - NWX2 - NWH8 - NWP8 - 256;
            bpp[j] = (j < PP) ? b_p[j] : 0.f;
        }
    }
}

__device__ __forceinline__ float decodeP(int rc, float p){
    if (rc < 64 || (rc >= 70 && rc < 134) || rc >= 204) return tanhf(p);
    if (rc >= 140 && rc < 204) return sigf(p);
    return p;
}

__global__ __launch_bounds__(1024,1) void ntm_kernel(
    const float* __restrict__ inputs,
    const float* __restrict__ W_o, const float* __restrict__ b_o,
    const float* __restrict__ r0, const float* __restrict__ w0,
    const uint4* __restrict__ wx2, const uint4* __restrict__ whi8,
    const uint4* __restrict__ wpi8,
    const float4* __restrict__ blh, const float* __restrict__ bpp,
    char* comm, float* __restrict__ out)
{
    const int bid = blockIdx.x, hf = bid>>7, b = bid&127;
    const int t = threadIdx.x, wv = t>>6, ln = t&63;
    const int g4 = t>>3, q = t&7;

    char* cb = comm + b*COMM_STRIDE;
    volatile float* hOwn = (volatile float*)(cb + hf*512);
    volatile float* hOth = (volatile float*)(cb + (hf^1)*512);
    volatile int*   flg  = (volatile int*)(cb + 2112);   // [f1A,f1B]

    __shared__ uint4 wxL[5120];          // 80KB pinned W_x half (fp16, conflict-free)
    __shared__ uint4 whL8[2][1024];      // 32KB pinned int8 W_h slices j=0,1
    __shared__ float Mem[NN][MM+1];
    __shared__ float4 gpart4[128];
    __shared__ float4 blhL[128];
    __shared__ float hbuf[U_];
    __shared__ float cbuf[128];
    __shared__ unsigned hq[64];          // h as int8 x4 words (unit 4j..4j+3)
    __shared__ h2_t  xr2[40] __attribute__((aligned(16)));
    __shared__ float prmS[12];
    __shared__ float scal[12];
    __shared__ float kv[2][MM], ebuf[MM], abuf[MM];
    __shared__ float innr[2][NN], Mn[NN], wgs[2][NN], wtab[2][NN];
    __shared__ float rpart[16][MM];
    __shared__ float jpart[OUT_];

    // ---- init ----
    for (int i=t; i<5120; i+=1024) wxL[i] = wx2[hf*5120 + i];
    for (int i=t; i<2048; i+=1024){
        int j = i>>10, jj = i&1023;
        whL8[j][jj] = whi8[hf*8192 + (jj>>3)*64 + j*8 + (jj&7)];
    }
    for (int i=t; i<NN*MM; i+=1024) Mem[i>>6][i&63] = 1e-6f;
    if (t < 128){
        gpart4[t] = make_float4(0.f,0.f,0.f,0.f);
        blhL[t] = blh[hf*128+t];
        cbuf[t] = 0.f;
        Mn[t] = 8e-6f;
    }
    if (t < 64) hq[t] = 0u;
    if (t < U_) hbuf[t] = 0.f;
    if (t >= 128 && t < 256){  // wtab = softmax(w0)
        int h = (t-128)>>6, l = t&63;
        float v0 = w0[h*NN + l], v1 = w0[h*NN + l + 64];
        float mx = fmaxf(v0,v1);
        for (int off=32; off>=1; off>>=1) mx = fmaxf(mx, __shfl_xor(mx, off));
        float e0 = __expf(v0-mx), e1 = __expf(v1-mx);
        float s = e0+e1;
        for (int off=32; off>=1; off>>=1) s += __shfl_xor(s, off);
        wtab[h][l] = e0/s; wtab[h][l+64] = e1/s;
    }
    if (t >= 256 && t < 296){
        int p = t-256;
        h2_t v;
        if (p < 32){ v.x = (_Float16)tanhf(r0[2*p]); v.y = (_Float16)tanhf(r0[2*p+1]); }
        else if (p < 37){
            int e0 = 2*(p-32), e1 = e0+1;
            float f0 = (e0<IN_DIM_) ? inputs[b*T_*IN_DIM_ + e0] : 0.f;
            float f1 = (e1<IN_DIM_) ? inputs[b*T_*IN_DIM_ + e1] : 0.f;
            v.x = (_Float16)f0; v.y = (_Float16)f1;
        } else { v.x=(_Float16)0.f; v.y=(_Float16)0.f; }
        xr2[p] = v;
    }
    __syncthreads();

    for (int step=0; step<T_; ++step){
        // ---- B: gates from pinned wx + gpart + bias, fused LSTM ----
        {
            const uint4* wb = wxL + wv*320;
            float a0=0.f,a1=0.f,a2=0.f,a3=0.f;
            #pragma unroll
            for (int p=0; p<5; ++p){
                uint4 u = wb[p*64 + ln];
                h2_t xv = xr2[q*5+p];
                DOT2X4(u, xv);
            }
            #pragma unroll
            for (int m=1; m<8; m<<=1){
                a0 += __shfl_xor(a0,m); a1 += __shfl_xor(a1,m);
                a2 += __shfl_xor(a2,m); a3 += __shfl_xor(a3,m);
            }
            if (q==0){
                float4 bb = blhL[g4]; float4 gp = gpart4[g4];
                float gi=a0+bb.x+gp.x, gf=a1+bb.y+gp.y, gg=a2+bb.z+gp.z, go=a3+bb.w+gp.w;
                float c = sigf(gf)*cbuf[g4] + sigf(gi)*tanhf(gg);
                cbuf[g4] = c;
                float h = sigf(go)*tanhf(c);
                hbuf[hf*128+g4] = h;
                hOwn[g4] = h;
            }
        }
        __syncthreads();                          // drains volatile h stores
        if (t==0){
            flg[hf] = step+1;
            while (flg[hf^1] < step+1) __builtin_amdgcn_s_sleep(8);
        }
        __syncthreads();
        // pull partner h; pack int8 h words
        if (t < 128){
            hbuf[(hf^1)*128 + t] = hOth[t];
        } else if (t < 160){
            const int jj = t-128;                  // own half word
            const float* hp = &hbuf[hf*128 + 4*jj];
            hq[hf*32 + jj] = packi8x4(hp[0], hp[1], hp[2], hp[3]);
        } else if (t < 192){
            const int jj = t-160;                  // partner half word (from comm)
            float h0 = hOth[4*jj], h1 = hOth[4*jj+1], h2 = hOth[4*jj+2], h3 = hOth[4*jj+3];
            hq[(hf^1)*32 + jj] = packi8x4(h0, h1, h2, h3);
        }
        __syncthreads();

        const int* hqi = (const int*)hq;

        // ---- FUSED: gpart (int8 sdot4) ; params int8 FULL (t<544) ; Mn ; jpart ; x-pre ----
        {
            const uint4* wrow = whi8 + hf*8192 + g4*64;
            int a0=0,a1=0,a2=0,a3=0;
            uint4 s2 = wrow[16+q], s3 = wrow[24+q], s4 = wrow[32+q];
            uint4 s5 = wrow[40+q], s6 = wrow[48+q], s7 = wrow[56+q];
            uint4 l0 = whL8[0][t], l1 = whL8[1][t];
            int hw0=hqi[q*8+0], hw1=hqi[q*8+1], hw2=hqi[q*8+2], hw3=hqi[q*8+3];
            int hw4=hqi[q*8+4], hw5=hqi[q*8+5], hw6=hqi[q*8+6], hw7=hqi[q*8+7];
            SD4(l0, hw0); SD4(l1, hw1);
            SD4(s2, hw2); SD4(s3, hw3);
            SD4(s4, hw4); SD4(s5, hw5);
            SD4(s6, hw6); SD4(s7, hw7);
            #pragma unroll
            for (int m=1; m<8; m<<=1){
                a0 += __shfl_xor(a0,m); a1 += __shfl_xor(a1,m);
                a2 += __shfl_xor(a2,m); a3 += __shfl_xor(a3,m);
            }
            if (q==0) gpart4[g4] = make_float4(a0*OSCALE, a1*OSCALE, a2*OSCALE, a3*OSCALE);
        }
        if (t < 544){
            const int cg = t>>3, qq = t&7;
            const uint4* wrow = wpi8 + cg*64;
            int pa0=0, pa1=0, pa2=0, pa3=0;
            uint4 u0=wrow[0*8+qq], u1=wrow[1*8+qq], u2=wrow[2*8+qq], u3=wrow[3*8+qq];
            uint4 u4=wrow[4*8+qq], u5=wrow[5*8+qq], u6=wrow[6*8+qq], u7=wrow[7*8+qq];
            int hw0=hqi[qq*8+0], hw1=hqi[qq*8+1], hw2=hqi[qq*8+2], hw3=hqi[qq*8+3];
            int hw4=hqi[qq*8+4], hw5=hqi[qq*8+5], hw6=hqi[qq*8+6], hw7=hqi[qq*8+7];
            SD4P(u0, hw0); SD4P(u1, hw1);
            SD4P(u2, hw2); SD4P(u3, hw3);
            SD4P(u4, hw4); SD4P(u5, hw5);
            SD4P(u6, hw6); SD4P(u7, hw7);
            #pragma unroll
            for (int m=1; m<8; m<<=1){
                pa0 += __shfl_xor(pa0,m); pa1 += __shfl_xor(pa1,m);
                pa2 += __shfl_xor(pa2,m); pa3 += __shfl_xor(pa3,m);
            }
            if (qq==0){
                #pragma unroll
                for (int j=0; j<4; ++j){
                    int aj = (j==0)?pa0:((j==1)?pa1:((j==2)?pa2:pa3));
                    int cl = cg*4+j;
                    if (cl < PP){
                        float pv = clipf(aj*OSCALE + bpp[cl]);
                        float dv = decodeP(cl, pv);
                        if (cl < 64) kv[0][cl] = dv;
                        else if (cl < 70) prmS[cl-64] = dv;
                        else if (cl < 134) kv[1][cl-70] = dv;
                        else if (cl < 140) prmS[6+cl-134] = dv;
                        else if (cl < 204) ebuf[cl-140] = dv;
                        else abuf[cl-204] = dv;
                    }
                }
            }
        } else if (t < 800){
            const int idx = t-544, n = idx>>1, m0 = (idx&1)*32;
            float s = 0.f;
            #pragma unroll 8
            for (int m=m0; m<m0+32; ++m){ float v=Mem[n][m]; s=fmaf(v,v,s); }
            s += __shfl_xor(s,1);
            if (!(idx&1)) Mn[n] = sqrtf(s);
        } else if (t < 928){
            const int o = (t-800)>>4, l16 = (t-800)&15;
            float s = 0.f;
            #pragma unroll
            for (int j=0; j<16; ++j){
                const int i = l16 + (j<<4);
                s = fmaf(hbuf[i], W_o[i*OUT_ + o], s);
            }
            s += __shfl_xor(s,1); s += __shfl_xor(s,2);
            s += __shfl_xor(s,4); s += __shfl_xor(s,8);
            if (l16==0) jpart[o] = s;
        } else if (t < 933){
            if (step+1 < T_){
                const int p = t-928;
                const int e0 = 2*p, e1 = e0+1;
                const float* xin = inputs + (b*T_ + step+1)*IN_DIM_;
                h2_t v;
                v.x = (_Float16)((e0<IN_DIM_) ? xin[e0] : 0.f);
                v.y = (_Float16)((e1<IN_DIM_) ? xin[e1] : 0.f);
                xr2[32+p] = v;
            }
        }
        __syncthreads();

        // ---- F: inner products + scal decode ----
        {
            const int h = t>>9, n = (t>>2)&127, qm = t&3, m0 = qm*16;
            float s = 0.f;
            #pragma unroll 8
            for (int m=m0; m<m0+16; ++m) s = fmaf(kv[h][m], Mem[n][m], s);
            s += __shfl_xor(s,1); s += __shfl_xor(s,2);
            if (qm==0) innr[h][n] = s;
        }
        if (t < 2){
            const int h = t;
            const float* ps = prmS + 6*h;
            scal[h]   = splus(ps[0]);
            scal[2+h] = sigf(ps[1]);
            float p0=ps[2], p1=ps[3], p2=ps[4];
            float mx = fmaxf(p0, fmaxf(p1, p2));
            float e0=__expf(p0-mx), e1=__expf(p1-mx), e2=__expf(p2-mx);
            float s = e0+e1+e2;
            scal[6+3*h]=e0/s; scal[7+3*h]=e1/s; scal[8+3*h]=e2/s;
            scal[4+h] = 1.f + splus(ps[5]);
        }
        __syncthreads();

        // ---- G: key norm + content softmax + interp + shift + sharpen ----
        if (t < 128){
            const int h = t>>6, l = ln;
            float kvl = kv[h][l];
            float kn2 = kvl*kvl;
            for (int off=32; off>=1; off>>=1) kn2 += __shfl_xor(kn2, off);
            float kn = sqrtf(kn2);
            float beta = scal[h], g = scal[2+h];
            float bk0 = beta * innr[h][l]   /(kn*Mn[l]   +1e-8f);
            float bk1 = beta * innr[h][l+64]/(kn*Mn[l+64]+1e-8f);
            float mx = fmaxf(bk0,bk1);
            for (int off=32; off>=1; off>>=1) mx = fmaxf(mx, __shfl_xor(mx, off));
            float e0=__expf(bk0-mx), e1=__expf(bk1-mx);
            float s=e0+e1;
            for (int off=32; off>=1; off>>=1) s += __shfl_xor(s, off);
            float wc0=e0/s, wc1=e1/s;
            wgs[h][l]    = g*wc0 + (1.f-g)*wtab[h][l];
            wgs[h][l+64] = g*wc1 + (1.f-g)*wtab[h][l+64];
            float gamma = scal[4+h];
            float s0=scal[6+3*h], s1=scal[7+3*h], s2=scal[8+3*h];
            const int n0=l, n1=l+64;
            float wt0 = s0*wgs[h][(n0+1)&127] + s1*wgs[h][n0] + s2*wgs[h][(n0+127)&127];
            float wt1 = s0*wgs[h][(n1+1)&127] + s1*wgs[h][n1] + s2*wgs[h][(n1+127)&127];
            float wp0 = __powf(wt0, gamma), wp1 = __powf(wt1, gamma);
            float ss = wp0+wp1;
            for (int off=32; off>=1; off>>=1) ss += __shfl_xor(ss, off);
            float inv = 1.0f/(ss+1e-8f);
            wtab[h][n0] = wp0*inv; wtab[h][n1] = wp1*inv;
        }
        __syncthreads();

        // ---- H: memory write + fused read-head partials ----
        {
            const float el = ebuf[ln], al = abuf[ln];
            const int n0 = wv*8;
            float racc = 0.f;
            #pragma unroll
            for (int k=0; k<8; ++k){
                const int n = n0+k;
                float ww = wtab[1][n];
                float wr = wtab[0][n];
                float v = Mem[n][ln]*(1.0f - ww*el) + ww*al;
                Mem[n][ln] = v;
                racc = fmaf(wr, v, racc);
            }
            rpart[wv][ln] = racc;
        }
        __syncthreads();

        // ---- J: r finalize + output (hf==0 writes) + xr2 r-pack ----
        if (t < 512){
            const int o = wv;
            float rm = 0.f;
            #pragma unroll
            for (int k=0; k<16; ++k) rm += rpart[k][ln];
            float s = rm * W_o[(U_+ln)*OUT_ + o];
            for (int off=32; off>=1; off>>=1) s += __shfl_xor(s, off);
            if (ln==0 && hf==0 && step>=TSTART){
                float logit = clipf(s + jpart[o] + b_o[o]);
                out[((b*(T_-TSTART)) + (step-TSTART))*OUT_ + o] = sigf(logit);
            }
        } else if (t < 576){
            float rm = 0.f;
            #pragma unroll
            for (int k=0; k<16; ++k) rm += rpart[k][ln];
            float other = __shfl_xor(rm, 1);
            if (!(ln&1)){
                h2_t v; v.x = (_Float16)rm; v.y = (_Float16)other;
                xr2[ln>>1] = v;
            }
        }
        __syncthreads();
    }
}

extern "C" void kernel_launch(void* const* d_in, const int* in_sizes, int n_in,
                              void* d_out, int out_size, void* d_ws, size_t ws_size,
                              hipStream_t stream) {
    const float* inputs = (const float*)d_in[0];
    const float* W_x    = (const float*)d_in[1];
    const float* W_h    = (const float*)d_in[2];
    const float* b_lstm = (const float*)d_in[3];
    const float* W_p    = (const float*)d_in[4];
    const float* b_p    = (const float*)d_in[5];
    const float* W_o    = (const float*)d_in[6];
    const float* b_o    = (const float*)d_in[7];
    const float* r0     = (const float*)d_in[8];
    const float* w0     = (const float*)d_in[9];
    float* out = (float*)d_out;

    char* ws = (char*)d_ws;
    uint4*  wx2 = (uint4*)(ws + WX2_OFF);
    uint4*  wh8 = (uint4*)(ws + WH8_OFF);
    uint4*  wp8 = (uint4*)(ws + WP8_OFF);
    float4* blh = (float4*)(ws + BLH_OFF);
    float*  bpp = (float*)(ws + BPP_OFF);
    char*   comm = ws + COMM_OFF;

    hipMemsetAsync(comm, 0, COMM_SZ, stream);
    prep_kernel<<<512, 256, 0, stream>>>(W_x, W_h, W_p, b_lstm, b_p, wx2, wh8, wp8, blh, bpp);
    ntm_kernel<<<2*B_, 1024, 0, stream>>>(inputs, W_o, b_o, r0, w0,
                                          wx2, wh8, wp8, blh, bpp, comm, out);
}

// Round 19
// 1559.121 us; speedup vs baseline: 1.9329x; 1.0345x over previous
//
#include <hip/hip_runtime.h>
#include <math.h>

typedef _Float16 h2_t __attribute__((ext_vector_type(2)));

#define U_ 256
#define NN 128
#define MM 64
#define OUT_ 8
#define CLIPV 20.0f
#define IN_DIM_ 9
#define PP 268
#define B_ 128
#define T_ 130
#define TSTART 65

// ws element counts / byte offsets
#define NWXI 6144       // 2hf * 16wv * 3j * 64ln      (uint4 int8, K=96 pad, kb=q*12+4j)
#define NWH8 16384      // 2hf * 128g4 * 64slot(j*8+q) (uint4 int8, kb=q*32+4j)
#define NWP8 4352       // 68cg * 64slot(j*8+q)        (uint4 int8, FULL width)
#define WXI_OFF 0
#define WH8_OFF 98304
#define WP8_OFF 360448
#define BLH_OFF 430080
#define BPP_OFF 434176
#define COMM_OFF 435264
#define COMM_STRIDE 2176          // hA512|hB512|(unused)|flags|pad
#define COMM_SZ (B_*COMM_STRIDE)
#define PREP_N (NWXI + NWH8 + NWP8 + 256 + 272)

#define WSCALE 256.f
#define HSCALE 127.f
#define OSCALE (1.f/(256.f*127.f))

__device__ __forceinline__ float sigf(float x){ return 1.0f/(1.0f+__expf(-x)); }
__device__ __forceinline__ float splus(float x){ return log1pf(__expf(x)); }
__device__ __forceinline__ float clipf(float x){ return fminf(fmaxf(x,-CLIPV),CLIPV); }

#if defined(__has_builtin)
#if __has_builtin(__builtin_amdgcn_sdot4)
#define SDOT4(a,b,c) __builtin_amdgcn_sdot4((a),(b),(c),false)
#endif
#endif
#ifndef SDOT4
__device__ __forceinline__ int sdot4_sw(int a, int b, int c){
    c += (int)(signed char)(a      ) * (int)(signed char)(b      );
    c += (int)(signed char)(a >> 8 ) * (int)(signed char)(b >> 8 );
    c += (int)(signed char)(a >> 16) * (int)(signed char)(b >> 16);
    c += (a >> 24) * (b >> 24);
    return c;
}
#define SDOT4(a,b,c) sdot4_sw((a),(b),(c))
#endif

#define SD4(u, hw) { \
    a0 = SDOT4((int)(u).x, hw, a0); a1 = SDOT4((int)(u).y, hw, a1); \
    a2 = SDOT4((int)(u).z, hw, a2); a3 = SDOT4((int)(u).w, hw, a3); }
#define SD4P(u, hw) { \
    pa0 = SDOT4((int)(u).x, hw, pa0); pa1 = SDOT4((int)(u).y, hw, pa1); \
    pa2 = SDOT4((int)(u).z, hw, pa2); pa3 = SDOT4((int)(u).w, hw, pa3); }

// encode w -> int8 byte of round(w*256), clamped
__device__ __forceinline__ unsigned ei8(float w){
    int v = (int)rintf(w * WSCALE);
    v = v < -127 ? -127 : (v > 127 ? 127 : v);
    return (unsigned)(v & 0xFF);
}

__device__ __forceinline__ unsigned packi8x4(float a, float b, float c, float d){
    int va = (int)rintf(a * HSCALE); va = va < -127 ? -127 : (va > 127 ? 127 : va);
    int vb = (int)rintf(b * HSCALE); vb = vb < -127 ? -127 : (vb > 127 ? 127 : vb);
    int vc = (int)rintf(c * HSCALE); vc = vc < -127 ? -127 : (vc > 127 ? 127 : vc);
    int vd = (int)rintf(d * HSCALE); vd = vd < -127 ? -127 : (vd > 127 ? 127 : vd);
    return (va & 0xFF) | ((vb & 0xFF) << 8) | ((vc & 0xFF) << 16) | ((vd & 0xFF) << 24);
}

__global__ void prep_kernel(const float* __restrict__ W_x, const float* __restrict__ W_h,
                            const float* __restrict__ W_p, const float* __restrict__ b_lstm,
                            const float* __restrict__ b_p,
                            uint4* __restrict__ wxi8, uint4* __restrict__ whi8,
                            uint4* __restrict__ wpi8,
                            float4* __restrict__ blh, float* __restrict__ bpp)
{
    for (int idx = blockIdx.x*blockDim.x + threadIdx.x; idx < PREP_N; idx += gridDim.x*blockDim.x){
        if (idx < NWXI){
            // int8 wx, ctrl order [r(64), x(9), pad]: [hf][wv][j][ln], kb=q*12+4j (K=96)
            int hf = idx/3072, rem = idx - hf*3072;
            int wv = rem/192, r2 = rem - wv*192, j = r2>>6, ln = r2&63;
            int g4 = wv*8 + (ln>>3), q = ln&7, kb = q*12 + 4*j;
            unsigned c[4];
            #pragma unroll
            for (int g=0; g<4; ++g){
                int col = g*256 + hf*128 + g4;
                unsigned w = 0;
                #pragma unroll
                for (int k=0; k<4; ++k){
                    int K = kb+k;
                    float f = (K<64) ? W_x[(9+K)*1024+col] : (K<73 ? W_x[(K-64)*1024+col] : 0.f);
                    w |= ei8(f) << (8*k);
                }
                c[g] = w;
            }
            wxi8[idx] = make_uint4(c[0],c[1],c[2],c[3]);
        } else if (idx < NWXI + NWH8){
            // int8 W_h: [hf][g4][slot j*8+q], kb=q*32+4j
            int e = idx - NWXI;
            int hf = e>>13, rem = e&8191, g4 = rem>>6, s = rem&63;
            int j = s>>3, q = s&7, kb = q*32 + 4*j;
            unsigned c[4];
            #pragma unroll
            for (int g=0; g<4; ++g){
                int col = g*256 + hf*128 + g4;
                c[g] = ei8(W_h[(kb+0)*1024+col])
                     | (ei8(W_h[(kb+1)*1024+col]) << 8)
                     | (ei8(W_h[(kb+2)*1024+col]) << 16)
                     | (ei8(W_h[(kb+3)*1024+col]) << 24);
            }
            whi8[e] = make_uint4(c[0],c[1],c[2],c[3]);
        } else if (idx < NWXI + NWH8 + NWP8){
            // int8 W_p FULL width: [cg][slot j*8+q], kb=q*32+4j
            int e = idx - NWXI - NWH8;
            int cg = e>>6, s = e&63;
            int j = s>>3, q = s&7, kb = q*32 + 4*j;
            unsigned c[4];
            #pragma unroll
            for (int g=0; g<4; ++g){
                int cl = cg*4+g;
                if (cl < PP){
                    c[g] = ei8(W_p[(kb+0)*PP+cl])
                         | (ei8(W_p[(kb+1)*PP+cl]) << 8)
                         | (ei8(W_p[(kb+2)*PP+cl]) << 16)
                         | (ei8(W_p[(kb+3)*PP+cl]) << 24);
                } else c[g] = 0u;
            }
            wpi8[e] = make_uint4(c[0],c[1],c[2],c[3]);
        } else if (idx < NWXI + NWH8 + NWP8 + 256){
            int u = idx - NWXI - NWH8 - NWP8;
            blh[u] = make_float4(b_lstm[u], b_lstm[256+u], b_lstm[512+u], b_lstm[768+u]);
        } else {
            int j = idx - NWXI - NWH8 - NWP8 - 256;
            bpp[j] = (j < PP) ? b_p[j] : 0.f;
        }
    }
}

__device__ __forceinline__ float decodeP(int rc, float p){
    if (rc < 64 || (rc >= 70 && rc < 134) || rc >= 204) return tanhf(p);
    if (rc >= 140 && rc < 204) return sigf(p);
    return p;
}

__global__ __launch_bounds__(1024,1) void ntm_kernel(
    const float* __restrict__ inputs,
    const float* __restrict__ W_o, const float* __restrict__ b_o,
    const float* __restrict__ r0, const float* __restrict__ w0,
    const uint4* __restrict__ wxi8, const uint4* __restrict__ whi8,
    const uint4* __restrict__ wpi8,
    const float4* __restrict__ blh, const float* __restrict__ bpp,
    char* comm, float* __restrict__ out)
{
    const int bid = blockIdx.x, hf = bid>>7, b = bid&127;
    const int t = threadIdx.x, wv = t>>6, ln = t&63;
    const int g4 = t>>3, q = t&7;

    char* cb = comm + b*COMM_STRIDE;
    volatile float* hOwn = (volatile float*)(cb + hf*512);
    volatile float* hOth = (volatile float*)(cb + (hf^1)*512);
    volatile int*   flg  = (volatile int*)(cb + 2112);   // [f1A,f1B]

    __shared__ uint4 wxL8[3072];         // 48KB pinned int8 wx half (conflict-free)
    __shared__ uint4 whL8[4][1024];      // 64KB pinned int8 W_h slices j=0..3
    __shared__ float Mem[NN][MM+1];
    __shared__ float4 gpart4[128];
    __shared__ float4 blhL[128];
    __shared__ float hbuf[U_];
    __shared__ float cbuf[128];
    __shared__ unsigned hq[64];          // h as int8 x4 words
    __shared__ unsigned xq[24];          // ctrl [r(16w), x(3w), pad(5w)] int8
    __shared__ float prmS[12];
    __shared__ float scal[12];
    __shared__ float kv[2][MM], ebuf[MM], abuf[MM];
    __shared__ float innr[2][NN], Mn[NN], wgs[2][NN], wtab[2][NN];
    __shared__ float rpart[16][MM];
    __shared__ float jpart[OUT_];

    // ---- init ----
    for (int i=t; i<3072; i+=1024) wxL8[i] = wxi8[hf*3072 + i];
    for (int i=t; i<4096; i+=1024){
        int j = i>>10, jj = i&1023;
        whL8[j][jj] = whi8[hf*8192 + (jj>>3)*64 + j*8 + (jj&7)];
    }
    for (int i=t; i<NN*MM; i+=1024) Mem[i>>6][i&63] = 1e-6f;
    if (t < 128){
        gpart4[t] = make_float4(0.f,0.f,0.f,0.f);
        blhL[t] = blh[hf*128+t];
        cbuf[t] = 0.f;
        Mn[t] = 8e-6f;
    }
    if (t < 64) hq[t] = 0u;
    if (t < U_) hbuf[t] = 0.f;
    if (t >= 128 && t < 256){  // wtab = softmax(w0)
        int h = (t-128)>>6, l = t&63;
        float v0 = w0[h*NN + l], v1 = w0[h*NN + l + 64];
        float mx = fmaxf(v0,v1);
        for (int off=32; off>=1; off>>=1) mx = fmaxf(mx, __shfl_xor(mx, off));
        float e0 = __expf(v0-mx), e1 = __expf(v1-mx);
        float s = e0+e1;
        for (int off=32; off>=1; off>>=1) s += __shfl_xor(s, off);
        wtab[h][l] = e0/s; wtab[h][l+64] = e1/s;
    }
    if (t >= 256 && t < 280){   // xq init: [r(16w from tanh r0), x(3w step0), zero]
        int p = t-256;
        if (p < 16){
            xq[p] = packi8x4(tanhf(r0[4*p]), tanhf(r0[4*p+1]), tanhf(r0[4*p+2]), tanhf(r0[4*p+3]));
        } else if (p < 19){
            const float* xin = inputs + b*T_*IN_DIM_;
            int e0 = 4*(p-16);
            float f0 = (e0+0<IN_DIM_) ? xin[e0+0] : 0.f;
            float f1 = (e0+1<IN_DIM_) ? xin[e0+1] : 0.f;
            float f2 = (e0+2<IN_DIM_) ? xin[e0+2] : 0.f;
            float f3 = (e0+3<IN_DIM_) ? xin[e0+3] : 0.f;
            xq[p] = packi8x4(f0,f1,f2,f3);
        } else xq[p] = 0u;
    }
    __syncthreads();

    for (int step=0; step<T_; ++step){
        const int* xqi = (const int*)xq;

        // ---- B: gates = xq . wxL8 (int8 sdot4) + gpart + bias, fused LSTM ----
        {
            const uint4* wb = wxL8 + wv*192;
            int a0=0,a1=0,a2=0,a3=0;
            #pragma unroll
            for (int j=0; j<3; ++j){
                uint4 u = wb[j*64 + ln];
                int xw = xqi[q*3+j];
                SD4(u, xw);
            }
            #pragma unroll
            for (int m=1; m<8; m<<=1){
                a0 += __shfl_xor(a0,m); a1 += __shfl_xor(a1,m);
                a2 += __shfl_xor(a2,m); a3 += __shfl_xor(a3,m);
            }
            if (q==0){
                float4 bb = blhL[g4]; float4 gp = gpart4[g4];
                float gi=a0*OSCALE+bb.x+gp.x, gf=a1*OSCALE+bb.y+gp.y;
                float gg=a2*OSCALE+bb.z+gp.z, go=a3*OSCALE+bb.w+gp.w;
                float c = sigf(gf)*cbuf[g4] + sigf(gi)*tanhf(gg);
                cbuf[g4] = c;
                float h = sigf(go)*tanhf(c);
                hbuf[hf*128+g4] = h;
                hOwn[g4] = h;
            }
        }
        __syncthreads();                          // drains volatile h stores
        if (t==0){
            flg[hf] = step+1;
            while (flg[hf^1] < step+1) __builtin_amdgcn_s_sleep(2);
        }
        __syncthreads();
        // pull partner h; pack int8 h words
        if (t < 128){
            hbuf[(hf^1)*128 + t] = hOth[t];
        } else if (t < 160){
            const int jj = t-128;                  // own half word
            const float* hp = &hbuf[hf*128 + 4*jj];
            hq[hf*32 + jj] = packi8x4(hp[0], hp[1], hp[2], hp[3]);
        } else if (t < 192){
            const int jj = t-160;                  // partner half word (from comm)
            float h0 = hOth[4*jj], h1 = hOth[4*jj+1], h2 = hOth[4*jj+2], h3 = hOth[4*jj+3];
            hq[(hf^1)*32 + jj] = packi8x4(h0, h1, h2, h3);
        }
        __syncthreads();

        const int* hqi = (const int*)hq;

        // ---- FUSED: gpart (4 LDS + 4 streamed) ; params int8 FULL ; Mn ; jpart ; x-pre ----
        {
            const uint4* wrow = whi8 + hf*8192 + g4*64;
            int a0=0,a1=0,a2=0,a3=0;
            uint4 s4 = wrow[32+q], s5 = wrow[40+q], s6 = wrow[48+q], s7 = wrow[56+q];
            uint4 l0 = whL8[0][t], l1 = whL8[1][t], l2 = whL8[2][t], l3 = whL8[3][t];
            int hw0=hqi[q*8+0], hw1=hqi[q*8+1], hw2=hqi[q*8+2], hw3=hqi[q*8+3];
            int hw4=hqi[q*8+4], hw5=hqi[q*8+5], hw6=hqi[q*8+6], hw7=hqi[q*8+7];
            SD4(l0, hw0); SD4(l1, hw1);
            SD4(l2, hw2); SD4(l3, hw3);
            SD4(s4, hw4); SD4(s5, hw5);
            SD4(s6, hw6); SD4(s7, hw7);
            #pragma unroll
            for (int m=1; m<8; m<<=1){
                a0 += __shfl_xor(a0,m); a1 += __shfl_xor(a1,m);
                a2 += __shfl_xor(a2,m); a3 += __shfl_xor(a3,m);
            }
            if (q==0) gpart4[g4] = make_float4(a0*OSCALE, a1*OSCALE, a2*OSCALE, a3*OSCALE);
        }
        if (t < 544){
            const int cg = t>>3, qq = t&7;
            const uint4* wrow = wpi8 + cg*64;
            int pa0=0, pa1=0, pa2=0, pa3=0;
            uint4 u0=wrow[0*8+qq], u1=wrow[1*8+qq], u2=wrow[2*8+qq], u3=wrow[3*8+qq];
            uint4 u4=wrow[4*8+qq], u5=wrow[5*8+qq], u6=wrow[6*8+qq], u7=wrow[7*8+qq];
            int hw0=hqi[qq*8+0], hw1=hqi[qq*8+1], hw2=hqi[qq*8+2], hw3=hqi[qq*8+3];
            int hw4=hqi[qq*8+4], hw5=hqi[qq*8+5], hw6=hqi[qq*8+6], hw7=hqi[qq*8+7];
            SD4P(u0, hw0); SD4P(u1, hw1);
            SD4P(u2, hw2); SD4P(u3, hw3);
            SD4P(u4, hw4); SD4P(u5, hw5);
            SD4P(u6, hw6); SD4P(u7, hw7);
            #pragma unroll
            for (int m=1; m<8; m<<=1){
                pa0 += __shfl_xor(pa0,m); pa1 += __shfl_xor(pa1,m);
                pa2 += __shfl_xor(pa2,m); pa3 += __shfl_xor(pa3,m);
            }
            if (qq==0){
                #pragma unroll
                for (int j=0; j<4; ++j){
                    int aj = (j==0)?pa0:((j==1)?pa1:((j==2)?pa2:pa3));
                    int cl = cg*4+j;
                    if (cl < PP){
                        float pv = clipf(aj*OSCALE + bpp[cl]);
                        float dv = decodeP(cl, pv);
                        if (cl < 64) kv[0][cl] = dv;
                        else if (cl < 70) prmS[cl-64] = dv;
                        else if (cl < 134) kv[1][cl-70] = dv;
                        else if (cl < 140) prmS[6+cl-134] = dv;
                        else if (cl < 204) ebuf[cl-140] = dv;
                        else abuf[cl-204] = dv;
                    }
                }
            }
        } else if (t < 800){
            const int idx = t-544, n = idx>>1, m0 = (idx&1)*32;
            float s = 0.f;
            #pragma unroll 8
            for (int m=m0; m<m0+32; ++m){ float v=Mem[n][m]; s=fmaf(v,v,s); }
            s += __shfl_xor(s,1);
            if (!(idx&1)) Mn[n] = sqrtf(s);
        } else if (t < 928){
            const int o = (t-800)>>4, l16 = (t-800)&15;
            float s = 0.f;
            #pragma unroll
            for (int j=0; j<16; ++j){
                const int i = l16 + (j<<4);
                s = fmaf(hbuf[i], W_o[i*OUT_ + o], s);
            }
            s += __shfl_xor(s,1); s += __shfl_xor(s,2);
            s += __shfl_xor(s,4); s += __shfl_xor(s,8);
            if (l16==0) jpart[o] = s;
        } else if (t < 931){
            if (step+1 < T_){
                const int p = t-928;                 // xq words 16..18 (x part)
                const float* xin = inputs + (b*T_ + step+1)*IN_DIM_;
                int e0 = 4*p;
                float f0 = (e0+0<IN_DIM_) ? xin[e0+0] : 0.f;
                float f1 = (e0+1<IN_DIM_) ? xin[e0+1] : 0.f;
                float f2 = (e0+2<IN_DIM_) ? xin[e0+2] : 0.f;
                float f3 = (e0+3<IN_DIM_) ? xin[e0+3] : 0.f;
                xq[16+p] = packi8x4(f0,f1,f2,f3);
            }
        }
        __syncthreads();

        // ---- F: inner products + scal decode ----
        {
            const int h = t>>9, n = (t>>2)&127, qm = t&3, m0 = qm*16;
            float s = 0.f;
            #pragma unroll 8
            for (int m=m0; m<m0+16; ++m) s = fmaf(kv[h][m], Mem[n][m], s);
            s += __shfl_xor(s,1); s += __shfl_xor(s,2);
            if (qm==0) innr[h][n] = s;
        }
        if (t < 2){
            const int h = t;
            const float* ps = prmS + 6*h;
            scal[h]   = splus(ps[0]);
            scal[2+h] = sigf(ps[1]);
            float p0=ps[2], p1=ps[3], p2=ps[4];
            float mx = fmaxf(p0, fmaxf(p1, p2));
            float e0=__expf(p0-mx), e1=__expf(p1-mx), e2=__expf(p2-mx);
            float s = e0+e1+e2;
            scal[6+3*h]=e0/s; scal[7+3*h]=e1/s; scal[8+3*h]=e2/s;
            scal[4+h] = 1.f + splus(ps[5]);
        }
        __syncthreads();

        // ---- G: key norm + content softmax + interp + shift + sharpen ----
        if (t < 128){
            const int h = t>>6, l = ln;
            float kvl = kv[h][l];
            float kn2 = kvl*kvl;
            for (int off=32; off>=1; off>>=1) kn2 += __shfl_xor(kn2, off);
            float kn = sqrtf(kn2);
            float beta = scal[h], g = scal[2+h];
            float bk0 = beta * innr[h][l]   /(kn*Mn[l]   +1e-8f);
            float bk1 = beta * innr[h][l+64]/(kn*Mn[l+64]+1e-8f);
            float mx = fmaxf(bk0,bk1);
            for (int off=32; off>=1; off>>=1) mx = fmaxf(mx, __shfl_xor(mx, off));
            float e0=__expf(bk0-mx), e1=__expf(bk1-mx);
            float s=e0+e1;
            for (int off=32; off>=1; off>>=1) s += __shfl_xor(s, off);
            float wc0=e0/s, wc1=e1/s;
            wgs[h][l]    = g*wc0 + (1.f-g)*wtab[h][l];
            wgs[h][l+64] = g*wc1 + (1.f-g)*wtab[h][l+64];
            float gamma = scal[4+h];
            float s0=scal[6+3*h], s1=scal[7+3*h], s2=scal[8+3*h];
            const int n0=l, n1=l+64;
            float wt0 = s0*wgs[h][(n0+1)&127] + s1*wgs[h][n0] + s2*wgs[h][(n0+127)&127];
            float wt1 = s0*wgs[h][(n1+1)&127] + s1*wgs[h][n1] + s2*wgs[h][(n1+127)&127];
            float wp0 = __powf(wt0, gamma), wp1 = __powf(wt1, gamma);
            float ss = wp0+wp1;
            for (int off=32; off>=1; off>>=1) ss += __shfl_xor(ss, off);
            float inv = 1.0f/(ss+1e-8f);
            wtab[h][n0] = wp0*inv; wtab[h][n1] = wp1*inv;
        }
        __syncthreads();

        // ---- H: memory write + fused read-head partials ----
        {
            const float el = ebuf[ln], al = abuf[ln];
            const int n0 = wv*8;
            float racc = 0.f;
            #pragma unroll
            for (int k=0; k<8; ++k){
                const int n = n0+k;
                float ww = wtab[1][n];
                float wr = wtab[0][n];
                float v = Mem[n][ln]*(1.0f - ww*el) + ww*al;
                Mem[n][ln] = v;
                racc = fmaf(wr, v, racc);
            }
            rpart[wv][ln] = racc;
        }
        __syncthreads();

        // ---- J: r finalize + output (hf==0 writes) + xq r-pack ----
        if (t < 512){
            const int o = wv;
            float rm = 0.f;
            #pragma unroll
            for (int k=0; k<16; ++k) rm += rpart[k][ln];
            float s = rm * W_o[(U_+ln)*OUT_ + o];
            for (int off=32; off>=1; off>>=1) s += __shfl_xor(s, off);
            if (ln==0 && hf==0 && step>=TSTART){
                float logit = clipf(s + jpart[o] + b_o[o]);
                out[((b*(T_-TSTART)) + (step-TSTART))*OUT_ + o] = sigf(logit);
            }
        } else if (t < 576){
            float rm = 0.f;
            #pragma unroll
            for (int k=0; k<16; ++k) rm += rpart[k][ln];
            float r1 = __shfl_down(rm, 1);
            float r2 = __shfl_down(rm, 2);
            float r3 = __shfl_down(rm, 3);
            if (!(ln&3)) xq[ln>>2] = packi8x4(rm, r1, r2, r3);
        }
        __syncthreads();
    }
}

extern "C" void kernel_launch(void* const* d_in, const int* in_sizes, int n_in,
                              void* d_out, int out_size, void* d_ws, size_t ws_size,
                              hipStream_t stream) {
    const float* inputs = (const float*)d_in[0];
    const float* W_x    = (const float*)d_in[1];
    const float* W_h    = (const float*)d_in[2];
    const float* b_lstm = (const float*)d_in[3];
    const float* W_p    = (const float*)d_in[4];
    const float* b_p    = (const float*)d_in[5];
    const float* W_o    = (const float*)d_in[6];
    const float* b_o    = (const float*)d_in[7];
    const float* r0     = (const float*)d_in[8];
    const float* w0     = (const float*)d_in[9];
    float* out = (float*)d_out;

    char* ws = (char*)d_ws;
    uint4*  wxi = (uint4*)(ws + WXI_OFF);
    uint4*  wh8 = (uint4*)(ws + WH8_OFF);
    uint4*  wp8 = (uint4*)(ws + WP8_OFF);
    float4* blh = (float4*)(ws + BLH_OFF);
    float*  bpp = (float*)(ws + BPP_OFF);
    char*   comm = ws + COMM_OFF;

    hipMemsetAsync(comm, 0, COMM_SZ, stream);
    prep_kernel<<<512, 256, 0, stream>>>(W_x, W_h, W_p, b_lstm, b_p, wxi, wh8, wp8, blh, bpp);
    ntm_kernel<<<2*B_, 1024, 0, stream>>>(inputs, W_o, b_o, r0, w0,
                                          wxi, wh8, wp8, blh, bpp, comm, out);
}